// Round 1
// baseline (622.874 us; speedup 1.0000x reference)
//
#include <hip/hip_runtime.h>
#include <stdint.h>

// ---------------- types / helpers ----------------
typedef short short8 __attribute__((ext_vector_type(8)));
typedef float f32x4 __attribute__((ext_vector_type(4)));

__device__ __forceinline__ unsigned short f2bf(float f) {
  union { float f; unsigned u; } v; v.f = f;
  unsigned u = v.u;
  u += 0x7fffu + ((u >> 16) & 1u);   // RNE
  return (unsigned short)(u >> 16);
}

__device__ __forceinline__ void gl16(const void* g, void* l) {
  __builtin_amdgcn_global_load_lds(
      (__attribute__((address_space(1))) void*)(uintptr_t)g,
      (__attribute__((address_space(3))) void*)l, 16, 0, 0);
}

// Problem constants
// B=8 CIN=512 COUT=512 H=W=64, K=3, pad=2 -> conv out 66x66
// padded spatial grid 68x68 per image: N = 8*68*68 = 36992
#define NSPAT 36992
#define PLANE 4624        // 68*68
#define XHP_ROWS 37152    // NSPAT + 160 margin rows

// ---------------- kernel 1: styles = w_lat @ aff_w^T / sqrt(512) + aff_b ----------------
__global__ void styles_kernel(const float* __restrict__ w_lat, const float* __restrict__ affw,
                              const float* __restrict__ affb, float* __restrict__ s) {
  int g = blockIdx.x * 256 + threadIdx.x;   // 0..4095
  int b = g >> 9, i = g & 511;
  const float4* wl = (const float4*)(w_lat + b * 512);
  const float4* aw = (const float4*)(affw + (size_t)i * 512);
  float acc = 0.f;
#pragma unroll 4
  for (int j = 0; j < 128; ++j) {
    float4 a = wl[j], c = aw[j];
    acc += a.x * c.x + a.y * c.y + a.z * c.z + a.w * c.w;
  }
  s[g] = acc * 0.044194173824159216f + affb[i];
}

// ---------------- kernel 2: global normalize s, write s and s2 ----------------
__global__ void norm_kernel(float* __restrict__ s, float* __restrict__ s2) {
  __shared__ float red[256];
  int t = threadIdx.x;
  float acc = 0.f;
  for (int e = t; e < 4096; e += 256) { float v = s[e]; acc += v * v; }
  red[t] = acc; __syncthreads();
  for (int st = 128; st > 0; st >>= 1) {
    if (t < st) red[t] += red[t + st];
    __syncthreads();
  }
  float alpha = rsqrtf(red[0] * (1.0f / 4096.0f));
  for (int e = t; e < 4096; e += 256) {
    float v = s[e] * alpha;
    s[e] = v; s2[e] = v * v;
  }
}

// ---------------- kernel 3: per-output-channel weight scale ----------------
__global__ void rowscale_kernel(const float* __restrict__ convw, float* __restrict__ rowscale) {
  int o = blockIdx.x, t = threadIdx.x;
  const float* wr = convw + (size_t)o * 4608;
  float acc = 0.f;
  for (int e = t; e < 4608; e += 256) { float v = wr[e]; acc += v * v; }
  __shared__ float red[256];
  red[t] = acc; __syncthreads();
  for (int st = 128; st > 0; st >>= 1) {
    if (t < st) red[t] += red[t + st];
    __syncthreads();
  }
  if (t == 0) rowscale[o] = rsqrtf(red[0] * (1.0f / 4608.0f));
}

// ---------------- kernel 4: build bf16 weights (tap, o, i) + W2[o][i] ----------------
__global__ void wprep_kernel(const float* __restrict__ convw, const float* __restrict__ rowscale,
                             unsigned short* __restrict__ wbf, float* __restrict__ W2) {
  int o = blockIdx.x, t = threadIdx.x;
  float sc = rowscale[o];
  for (int i = t; i < 512; i += 256) {
    const float* wp = convw + ((size_t)o * 512 + i) * 9;
    float w9[9]; float ss = 0.f;
#pragma unroll
    for (int m = 0; m < 9; ++m) { float v = wp[m] * sc; w9[m] = v; ss += v * v; }
    W2[((size_t)o << 9) + i] = ss;
#pragma unroll
    for (int m = 0; m < 9; ++m)
      wbf[(((size_t)m * 512 + o) << 9) + i] = f2bf(w9[m]);
  }
}

// ---------------- kernel 5: demod d[b][o] ----------------
__global__ void demod_kernel(const float* __restrict__ s2, const float* __restrict__ W2,
                             float* __restrict__ dbuf) {
  int g = blockIdx.x * 256 + threadIdx.x;  // b*512+o
  int b = g >> 9, o = g & 511;
  const float4* sp = (const float4*)(s2 + b * 512);
  const float4* wp = (const float4*)(W2 + (size_t)o * 512);
  float acc = 1e-8f;
#pragma unroll 4
  for (int j = 0; j < 128; ++j) {
    float4 a = sp[j], c = wp[j];
    acc += a.x * c.x + a.y * c.y + a.z * c.z + a.w * c.w;
  }
  dbuf[g] = rsqrtf(acc);
}

// ---------------- kernel 6: x-hat NHWC padded bf16 : xhp[b][h+2][w+2][i] = bf16(x*s) ----------------
__global__ void xprep_kernel(const float* __restrict__ x, const float* __restrict__ s,
                             unsigned short* __restrict__ xhp) {
  int b = blockIdx.x >> 6, h = blockIdx.x & 63;
  int t = threadIdx.x;
  __shared__ float tile[64 * 65];
  __shared__ float sv[64];
  for (int it = 0; it < 8; ++it) {
    int i0 = it * 64;
    {
      int ii = t >> 2, wseg = (t & 3) * 16;
      const float4* src = (const float4*)(x + (((size_t)(b * 512 + i0 + ii) * 64 + h) << 6) + wseg);
      float4 v0 = src[0], v1 = src[1], v2 = src[2], v3 = src[3];
      float* dst = tile + ii * 65 + wseg;
      dst[0]=v0.x; dst[1]=v0.y; dst[2]=v0.z; dst[3]=v0.w;
      dst[4]=v1.x; dst[5]=v1.y; dst[6]=v1.z; dst[7]=v1.w;
      dst[8]=v2.x; dst[9]=v2.y; dst[10]=v2.z; dst[11]=v2.w;
      dst[12]=v3.x; dst[13]=v3.y; dst[14]=v3.z; dst[15]=v3.w;
    }
    if (t < 64) sv[t] = s[b * 512 + i0 + t];
    __syncthreads();
    {
      int w = t >> 2, ic = (t & 3) * 16;
      alignas(16) unsigned short tmp[16];
#pragma unroll
      for (int k = 0; k < 16; ++k)
        tmp[k] = f2bf(tile[(ic + k) * 65 + w] * sv[ic + k]);
      unsigned short* dst = xhp + ((size_t)b * PLANE + (h + 2) * 68 + (w + 2)) * 512 + i0 + ic;
      *(short8*)dst = *(const short8*)tmp;
      *(short8*)(dst + 8) = *(const short8*)(tmp + 8);
    }
    __syncthreads();
  }
}

// ---------------- kernel 7: implicit-GEMM conv, M=512(o) x N=36992(spatial), K=9*512 ----------------
// A = wbf (tap,o,i), B = xhp NHWC padded; epilogue: *d[b,o] + bias[o], clamp +-256
// ybuf layout [o][n] fp32 (n over padded 68x68 grid)
__global__ __launch_bounds__(256) void conv_kernel(const unsigned short* __restrict__ wbf,
                                                   const unsigned short* __restrict__ xhp,
                                                   const float* __restrict__ dbuf,
                                                   const float* __restrict__ convb,
                                                   float* __restrict__ ybuf) {
  __shared__ unsigned short lds[8192];   // A: [0,4096) shorts, B: [4096,8192)
  const int t = threadIdx.x;
  const int lane = t & 63, wid = t >> 6;
  const int n0 = blockIdx.x * 128, o0 = blockIdx.y * 128;
  const int wm = wid >> 1, wn = wid & 1;

  const unsigned kc = (lane & 3) * 8;
  const unsigned aOff0 = (unsigned)(o0 + wid * 32 + (lane >> 2)) * 512 + kc;
  const unsigned aOff1 = aOff0 + 16 * 512;
  const unsigned bOff0 = (unsigned)(n0 + wid * 32 + (lane >> 2)) * 512 + kc;
  const unsigned bOff1 = bOff0 + 16 * 512;

  unsigned short* ldsA = lds;
  unsigned short* ldsB = lds + 4096;
  unsigned short* lA0 = ldsA + wid * 1024;
  unsigned short* lA1 = lA0 + 512;
  unsigned short* lB0 = ldsB + wid * 1024;
  unsigned short* lB1 = lB0 + 512;

  const unsigned short* aF = ldsA + wm * 2048 + (lane & 15) * 32 + (lane >> 4) * 8;
  const unsigned short* bF = ldsB + wn * 2048 + (lane & 15) * 32 + (lane >> 4) * 8;

  f32x4 acc[4][4] = {};

  for (int tap = 0; tap < 9; ++tap) {
    const unsigned aTap = (unsigned)tap * 262144;                 // tap*512*512
    const unsigned bShift = (unsigned)((tap / 3) * 68 + (tap % 3)) * 512;
    for (int ks = 0; ks < 16; ++ks) {
      const unsigned k0 = ks * 32;
      gl16(wbf + aTap + aOff0 + k0, lA0);
      gl16(wbf + aTap + aOff1 + k0, lA1);
      gl16(xhp + bShift + bOff0 + k0, lB0);
      gl16(xhp + bShift + bOff1 + k0, lB1);
      __syncthreads();

      short8 a0 = *(const short8*)(aF + 0);
      short8 a1 = *(const short8*)(aF + 512);
      short8 a2 = *(const short8*)(aF + 1024);
      short8 a3 = *(const short8*)(aF + 1536);
      short8 b0 = *(const short8*)(bF + 0);
      short8 b1 = *(const short8*)(bF + 512);
      short8 b2 = *(const short8*)(bF + 1024);
      short8 b3 = *(const short8*)(bF + 1536);

      acc[0][0] = __builtin_amdgcn_mfma_f32_16x16x32_bf16(a0, b0, acc[0][0], 0, 0, 0);
      acc[0][1] = __builtin_amdgcn_mfma_f32_16x16x32_bf16(a0, b1, acc[0][1], 0, 0, 0);
      acc[0][2] = __builtin_amdgcn_mfma_f32_16x16x32_bf16(a0, b2, acc[0][2], 0, 0, 0);
      acc[0][3] = __builtin_amdgcn_mfma_f32_16x16x32_bf16(a0, b3, acc[0][3], 0, 0, 0);
      acc[1][0] = __builtin_amdgcn_mfma_f32_16x16x32_bf16(a1, b0, acc[1][0], 0, 0, 0);
      acc[1][1] = __builtin_amdgcn_mfma_f32_16x16x32_bf16(a1, b1, acc[1][1], 0, 0, 0);
      acc[1][2] = __builtin_amdgcn_mfma_f32_16x16x32_bf16(a1, b2, acc[1][2], 0, 0, 0);
      acc[1][3] = __builtin_amdgcn_mfma_f32_16x16x32_bf16(a1, b3, acc[1][3], 0, 0, 0);
      acc[2][0] = __builtin_amdgcn_mfma_f32_16x16x32_bf16(a2, b0, acc[2][0], 0, 0, 0);
      acc[2][1] = __builtin_amdgcn_mfma_f32_16x16x32_bf16(a2, b1, acc[2][1], 0, 0, 0);
      acc[2][2] = __builtin_amdgcn_mfma_f32_16x16x32_bf16(a2, b2, acc[2][2], 0, 0, 0);
      acc[2][3] = __builtin_amdgcn_mfma_f32_16x16x32_bf16(a2, b3, acc[2][3], 0, 0, 0);
      acc[3][0] = __builtin_amdgcn_mfma_f32_16x16x32_bf16(a3, b0, acc[3][0], 0, 0, 0);
      acc[3][1] = __builtin_amdgcn_mfma_f32_16x16x32_bf16(a3, b1, acc[3][1], 0, 0, 0);
      acc[3][2] = __builtin_amdgcn_mfma_f32_16x16x32_bf16(a3, b2, acc[3][2], 0, 0, 0);
      acc[3][3] = __builtin_amdgcn_mfma_f32_16x16x32_bf16(a3, b3, acc[3][3], 0, 0, 0);
      __syncthreads();
    }
  }

  // epilogue
  const int col = lane & 15;
  const int rbase = (lane >> 4) * 4;
#pragma unroll
  for (int ni = 0; ni < 4; ++ni) {
    const unsigned n = (unsigned)(n0 + wn * 64 + ni * 16 + col);
    const unsigned b = n / 4624u;
    const float* dr = dbuf + b * 512;
#pragma unroll
    for (int mi = 0; mi < 4; ++mi) {
      const int ob = o0 + wm * 64 + mi * 16 + rbase;
#pragma unroll
      for (int j = 0; j < 4; ++j) {
        const int o = ob + j;
        float v = acc[mi][ni][j] * dr[o] + convb[o];
        v = fminf(fmaxf(v, -256.f), 256.f);
        ybuf[(size_t)o * NSPAT + n] = v;
      }
    }
  }
}

// ---------------- kernel 8: fused upfirdn up2 + lrelu + upfirdn down2 (per channel) ----------------
// LDS plan (floats): uB[66*67]=4422 | uhB[66*138]=9108 | zB[138*138]=19044 ; dhB overlays offset 0 (8970)
__global__ void updown_kernel(const float* __restrict__ ybuf, const float* __restrict__ upf,
                              const float* __restrict__ dnf, float* __restrict__ out) {
  extern __shared__ float sm[];
  float* uB = sm;
  float* uhB = sm + 4422;
  float* zB = sm + 13530;
  float* dhB = sm;

  const int ch = blockIdx.x;
  const int o = ch & 511, b = ch >> 9;
  const float* ybase = ybuf + (size_t)o * NSPAT + b * PLANE;
  const int t = threadIdx.x;

  float f2[12], g[12];
#pragma unroll
  for (int m = 0; m < 12; ++m) { f2[m] = upf[11 - m] * 2.0f; g[m] = dnf[11 - m]; }

  // P1: load u (66x66) from ybuf (68-stride plane)
  for (int e = t; e < 4356; e += 256) {
    int p = e / 66, q = e - p * 66;
    uB[p * 67 + q] = ybase[p * 68 + q];
  }
  __syncthreads();

  // P2: horizontal upsample: uh[p][c], c=0..137
  if (t < 198) {
    int p = t % 66, third = t / 66;
    int e0 = third * 23;
    const float* ur = uB + p * 67;
    float* uhr = uhB + p * 138;
    float w[6];
#pragma unroll
    for (int r = 0; r < 6; ++r) {
      int j = e0 - 4 + r;
      w[r] = (j >= 0 && j < 66) ? ur[j] : 0.f;
    }
    for (int e = e0; e < e0 + 23; ++e) {
      float ev = f2[1]*w[0] + f2[3]*w[1] + f2[5]*w[2] + f2[7]*w[3] + f2[9]*w[4] + f2[11]*w[5];
      float od = f2[0]*w[0] + f2[2]*w[1] + f2[4]*w[2] + f2[6]*w[3] + f2[8]*w[4] + f2[10]*w[5];
      uhr[2 * e] = ev;
      uhr[2 * e + 1] = od;
      w[0]=w[1]; w[1]=w[2]; w[2]=w[3]; w[3]=w[4]; w[4]=w[5];
      int jn = e + 2;
      w[5] = (jn < 66) ? ur[jn] : 0.f;
    }
  }
  __syncthreads();

  // P3: vertical upsample + lrelu*sqrt2 + clamp -> z[tt][c]
  if (t < 138) {
    const int c = t;
    float w[6];
#pragma unroll
    for (int r = 0; r < 6; ++r) {
      int j = r - 4;
      w[r] = (j >= 0) ? uhB[j * 138 + c] : 0.f;
    }
    for (int e = 0; e < 69; ++e) {
      float ev = f2[1]*w[0] + f2[3]*w[1] + f2[5]*w[2] + f2[7]*w[3] + f2[9]*w[4] + f2[11]*w[5];
      float od = f2[0]*w[0] + f2[2]*w[1] + f2[4]*w[2] + f2[6]*w[3] + f2[8]*w[4] + f2[10]*w[5];
      ev = (ev > 0.f ? ev : 0.2f * ev) * 1.4142135623730951f;
      od = (od > 0.f ? od : 0.2f * od) * 1.4142135623730951f;
      ev = fminf(fmaxf(ev, -256.f), 256.f);
      od = fminf(fmaxf(od, -256.f), 256.f);
      zB[(2 * e) * 138 + c] = ev;
      zB[(2 * e + 1) * 138 + c] = od;
      w[0]=w[1]; w[1]=w[2]; w[2]=w[3]; w[3]=w[4]; w[4]=w[5];
      int jn = e + 2;
      w[5] = (jn < 66) ? uhB[jn * 138 + c] : 0.f;
    }
  }
  __syncthreads();

  // P4: horizontal downsample: dh[tt][r], r=0..63
  if (t < 138) {
    const float* zr = zB + t * 138;
    float* dhr = dhB + t * 65;
    float w[12];
#pragma unroll
    for (int m = 0; m < 12; ++m) w[m] = zr[m];
    for (int r = 0; r < 64; ++r) {
      float v = g[0]*w[0] + g[1]*w[1] + g[2]*w[2] + g[3]*w[3] + g[4]*w[4] + g[5]*w[5]
              + g[6]*w[6] + g[7]*w[7] + g[8]*w[8] + g[9]*w[9] + g[10]*w[10] + g[11]*w[11];
      dhr[r] = v;
#pragma unroll
      for (int m = 0; m < 10; ++m) w[m] = w[m + 2];
      int i0 = 2 * r + 12; if (i0 > 137) i0 = 137;
      int i1 = 2 * r + 13; if (i1 > 137) i1 = 137;
      w[10] = zr[i0];
      w[11] = zr[i1];
    }
  }
  __syncthreads();

  // P5: vertical downsample -> out[s][r]
  {
    const int r = t & 63, sq = t >> 6;
    const int s0 = sq * 16;
    float w[12];
#pragma unroll
    for (int m = 0; m < 12; ++m) w[m] = dhB[(2 * s0 + m) * 65 + r];
    float* ob = out + ((size_t)(b * 512 + o) * 64) * 64 + r;
    for (int s = s0; s < s0 + 16; ++s) {
      float v = g[0]*w[0] + g[1]*w[1] + g[2]*w[2] + g[3]*w[3] + g[4]*w[4] + g[5]*w[5]
              + g[6]*w[6] + g[7]*w[7] + g[8]*w[8] + g[9]*w[9] + g[10]*w[10] + g[11]*w[11];
      ob[(size_t)s * 64] = v;
#pragma unroll
      for (int m = 0; m < 10; ++m) w[m] = w[m + 2];
      int i0 = 2 * s + 12; if (i0 > 137) i0 = 137;
      int i1 = 2 * s + 13; if (i1 > 137) i1 = 137;
      w[10] = dhB[i0 * 65 + r];
      w[11] = dhB[i1 * 65 + r];
    }
  }
}

// ---------------- launcher ----------------
extern "C" void kernel_launch(void* const* d_in, const int* in_sizes, int n_in,
                              void* d_out, int out_size, void* d_ws, size_t ws_size,
                              hipStream_t stream) {
  const float* x     = (const float*)d_in[0];
  const float* w_lat = (const float*)d_in[1];
  const float* convw = (const float*)d_in[2];
  const float* convb = (const float*)d_in[3];
  const float* affw  = (const float*)d_in[4];
  const float* affb  = (const float*)d_in[5];
  const float* upf   = (const float*)d_in[6];
  const float* dnf   = (const float*)d_in[7];
  float* out = (float*)d_out;

  char* ws = (char*)d_ws;
  float* s         = (float*)(ws + 0);
  float* s2        = (float*)(ws + 16384);
  float* rowscale  = (float*)(ws + 32768);
  float* W2        = (float*)(ws + 34816);
  float* dbuf      = (float*)(ws + 1083392);
  unsigned short* wbf = (unsigned short*)(ws + 1099776);
  unsigned short* xhp = (unsigned short*)(ws + 5818368);
  float* ybuf      = (float*)(ws + 43862016);

  styles_kernel<<<16, 256, 0, stream>>>(w_lat, affw, affb, s);
  norm_kernel<<<1, 256, 0, stream>>>(s, s2);
  rowscale_kernel<<<512, 256, 0, stream>>>(convw, rowscale);
  wprep_kernel<<<512, 256, 0, stream>>>(convw, rowscale, wbf, W2);
  demod_kernel<<<16, 256, 0, stream>>>(s2, W2, dbuf);

  hipMemsetAsync(xhp, 0, (size_t)XHP_ROWS * 512 * 2, stream);
  xprep_kernel<<<512, 256, 0, stream>>>(x, s, xhp);

  dim3 cgrid(289, 4);
  conv_kernel<<<cgrid, 256, 0, stream>>>(wbf, xhp, dbuf, convb, ybuf);

  updown_kernel<<<4096, 256, 130296, stream>>>(ybuf, upf, dnf, out);
}

// Round 2
// 470.947 us; speedup vs baseline: 1.3226x; 1.3226x over previous
//
#include <hip/hip_runtime.h>
#include <stdint.h>

// ---------------- types / helpers ----------------
typedef short short8 __attribute__((ext_vector_type(8)));
typedef float f32x4 __attribute__((ext_vector_type(4)));

__device__ __forceinline__ unsigned short f2bf(float f) {
  union { float f; unsigned u; } v; v.f = f;
  unsigned u = v.u;
  u += 0x7fffu + ((u >> 16) & 1u);   // RNE
  return (unsigned short)(u >> 16);
}

__device__ __forceinline__ void gl16(const void* g, void* l) {
  __builtin_amdgcn_global_load_lds(
      (__attribute__((address_space(1))) void*)(uintptr_t)g,
      (__attribute__((address_space(3))) void*)l, 16, 0, 0);
}

// Problem constants
// B=8 CIN=512 COUT=512 H=W=64, K=3, pad=2 -> conv out 66x66
// padded spatial grid 68x68 per image: N = 8*68*68 = 36992
#define NSPAT 36992
#define PLANE 4624        // 68*68
#define XHP_ROWS 37152    // NSPAT + 160 margin rows

// ---------------- kernel 1: styles = w_lat @ aff_w^T / sqrt(512) + aff_b ----------------
__global__ void styles_kernel(const float* __restrict__ w_lat, const float* __restrict__ affw,
                              const float* __restrict__ affb, float* __restrict__ s) {
  int g = blockIdx.x * 256 + threadIdx.x;   // 0..4095
  int b = g >> 9, i = g & 511;
  const float4* wl = (const float4*)(w_lat + b * 512);
  const float4* aw = (const float4*)(affw + (size_t)i * 512);
  float acc = 0.f;
#pragma unroll 4
  for (int j = 0; j < 128; ++j) {
    float4 a = wl[j], c = aw[j];
    acc += a.x * c.x + a.y * c.y + a.z * c.z + a.w * c.w;
  }
  s[g] = acc * 0.044194173824159216f + affb[i];
}

// ---------------- kernel 2: global normalize s, write s and s2 ----------------
__global__ void norm_kernel(float* __restrict__ s, float* __restrict__ s2) {
  __shared__ float red[256];
  int t = threadIdx.x;
  float acc = 0.f;
  for (int e = t; e < 4096; e += 256) { float v = s[e]; acc += v * v; }
  red[t] = acc; __syncthreads();
  for (int st = 128; st > 0; st >>= 1) {
    if (t < st) red[t] += red[t + st];
    __syncthreads();
  }
  float alpha = rsqrtf(red[0] * (1.0f / 4096.0f));
  for (int e = t; e < 4096; e += 256) {
    float v = s[e] * alpha;
    s[e] = v; s2[e] = v * v;
  }
}

// ---------------- kernel 3: per-output-channel weight scale ----------------
__global__ void rowscale_kernel(const float* __restrict__ convw, float* __restrict__ rowscale) {
  int o = blockIdx.x, t = threadIdx.x;
  const float* wr = convw + (size_t)o * 4608;
  float acc = 0.f;
  for (int e = t; e < 4608; e += 256) { float v = wr[e]; acc += v * v; }
  __shared__ float red[256];
  red[t] = acc; __syncthreads();
  for (int st = 128; st > 0; st >>= 1) {
    if (t < st) red[t] += red[t + st];
    __syncthreads();
  }
  if (t == 0) rowscale[o] = rsqrtf(red[0] * (1.0f / 4608.0f));
}

// ---------------- kernel 4: build bf16 weights (tap, o, i) + W2[o][i] ----------------
__global__ void wprep_kernel(const float* __restrict__ convw, const float* __restrict__ rowscale,
                             unsigned short* __restrict__ wbf, float* __restrict__ W2) {
  int o = blockIdx.x, t = threadIdx.x;
  float sc = rowscale[o];
  for (int i = t; i < 512; i += 256) {
    const float* wp = convw + ((size_t)o * 512 + i) * 9;
    float w9[9]; float ss = 0.f;
#pragma unroll
    for (int m = 0; m < 9; ++m) { float v = wp[m] * sc; w9[m] = v; ss += v * v; }
    W2[((size_t)o << 9) + i] = ss;
#pragma unroll
    for (int m = 0; m < 9; ++m)
      wbf[(((size_t)m * 512 + o) << 9) + i] = f2bf(w9[m]);
  }
}

// ---------------- kernel 5: demod d[b][o] ----------------
__global__ void demod_kernel(const float* __restrict__ s2, const float* __restrict__ W2,
                             float* __restrict__ dbuf) {
  int g = blockIdx.x * 256 + threadIdx.x;  // b*512+o
  int b = g >> 9, o = g & 511;
  const float4* sp = (const float4*)(s2 + b * 512);
  const float4* wp = (const float4*)(W2 + (size_t)o * 512);
  float acc = 1e-8f;
#pragma unroll 4
  for (int j = 0; j < 128; ++j) {
    float4 a = sp[j], c = wp[j];
    acc += a.x * c.x + a.y * c.y + a.z * c.z + a.w * c.w;
  }
  dbuf[g] = rsqrtf(acc);
}

// ---------------- kernel 6: x-hat NHWC padded bf16 : xhp[b][h+2][w+2][i] = bf16(x*s) ----------------
__global__ void xprep_kernel(const float* __restrict__ x, const float* __restrict__ s,
                             unsigned short* __restrict__ xhp) {
  int b = blockIdx.x >> 6, h = blockIdx.x & 63;
  int t = threadIdx.x;
  __shared__ float tile[64 * 65];
  __shared__ float sv[64];
  for (int it = 0; it < 8; ++it) {
    int i0 = it * 64;
    {
      int ii = t >> 2, wseg = (t & 3) * 16;
      const float4* src = (const float4*)(x + (((size_t)(b * 512 + i0 + ii) * 64 + h) << 6) + wseg);
      float4 v0 = src[0], v1 = src[1], v2 = src[2], v3 = src[3];
      float* dst = tile + ii * 65 + wseg;
      dst[0]=v0.x; dst[1]=v0.y; dst[2]=v0.z; dst[3]=v0.w;
      dst[4]=v1.x; dst[5]=v1.y; dst[6]=v1.z; dst[7]=v1.w;
      dst[8]=v2.x; dst[9]=v2.y; dst[10]=v2.z; dst[11]=v2.w;
      dst[12]=v3.x; dst[13]=v3.y; dst[14]=v3.z; dst[15]=v3.w;
    }
    if (t < 64) sv[t] = s[b * 512 + i0 + t];
    __syncthreads();
    {
      int w = t >> 2, ic = (t & 3) * 16;
      alignas(16) unsigned short tmp[16];
#pragma unroll
      for (int k = 0; k < 16; ++k)
        tmp[k] = f2bf(tile[(ic + k) * 65 + w] * sv[ic + k]);
      unsigned short* dst = xhp + ((size_t)b * PLANE + (h + 2) * 68 + (w + 2)) * 512 + i0 + ic;
      *(short8*)dst = *(const short8*)tmp;
      *(short8*)(dst + 8) = *(const short8*)(tmp + 8);
    }
    __syncthreads();
  }
}

// ---------------- kernel 7: implicit-GEMM conv, 128x128 tile, 2-phase dbuf prefetch ----------------
// A = wbf (tap,o,i), B = xhp NHWC padded; epilogue: *d[b,o] + bias[o], clamp +-256
__global__ __launch_bounds__(256, 3) void conv_kernel(const unsigned short* __restrict__ wbf,
                                                      const unsigned short* __restrict__ xhp,
                                                      const float* __restrict__ dbuf,
                                                      const float* __restrict__ convb,
                                                      float* __restrict__ ybuf) {
  __shared__ unsigned short lds[16384];  // A dbuf: [0,8192) ; B dbuf: [8192,16384)
  const int t = threadIdx.x;
  const int lane = t & 63, wid = t >> 6;

  // bijective XCD swizzle: nwg=1156, q=144, r=4; wg order = otile*289 + ntile
  int orig = blockIdx.y * 289 + blockIdx.x;
  int xcd = orig & 7, idx = orig >> 3;
  int wg = (xcd < 4) ? (xcd * 145 + idx) : (580 + (xcd - 4) * 144 + idx);
  const int n0 = (wg % 289) * 128, o0 = (wg / 289) * 128;
  const int wm = wid >> 1, wn = wid & 1;

  const unsigned kc = (lane & 3) * 8;
  const unsigned aOff0 = (unsigned)(o0 + wid * 32 + (lane >> 2)) * 512 + kc;
  const unsigned aOff1 = aOff0 + 16 * 512;
  const unsigned bOff0 = (unsigned)(n0 + wid * 32 + (lane >> 2)) * 512 + kc;
  const unsigned bOff1 = bOff0 + 16 * 512;

  unsigned short* const lAw = lds + wid * 1024;          // + buf*4096
  unsigned short* const lBw = lds + 8192 + wid * 1024;   // + buf*4096

  const unsigned aFo = wm * 2048 + (lane & 15) * 32 + (lane >> 4) * 8;
  const unsigned bFo = 8192 + wn * 2048 + (lane & 15) * 32 + (lane >> 4) * 8;

  f32x4 acc[4][4] = {};

#define STAGE(stp, bf) do {                                           \
    const unsigned tp = (unsigned)(stp) >> 4;                          \
    const unsigned k0 = ((unsigned)(stp) & 15u) * 32u;                 \
    const unsigned aT = tp * 262144u + k0;                             \
    const unsigned bS = ((tp / 3u) * 68u + (tp % 3u)) * 512u + k0;     \
    unsigned short* la = lAw + (bf) * 4096;                            \
    unsigned short* lb = lBw + (bf) * 4096;                            \
    gl16(wbf + aT + aOff0, la);                                        \
    gl16(wbf + aT + aOff1, la + 512);                                  \
    gl16(xhp + bS + bOff0, lb);                                        \
    gl16(xhp + bS + bOff1, lb + 512);                                  \
  } while (0)

  STAGE(0, 0);
  __syncthreads();
  int cur = 0;
  for (int step = 0; step < 144; ++step) {
    if (step < 143) STAGE(step + 1, cur ^ 1);   // prefetch next tile (in flight across compute)

    const unsigned short* aF = lds + cur * 4096 + aFo;
    const unsigned short* bF = lds + cur * 4096 + bFo;
    short8 a0 = *(const short8*)(aF + 0);
    short8 a1 = *(const short8*)(aF + 512);
    short8 a2 = *(const short8*)(aF + 1024);
    short8 a3 = *(const short8*)(aF + 1536);
    short8 b0 = *(const short8*)(bF + 0);
    short8 b1 = *(const short8*)(bF + 512);
    short8 b2 = *(const short8*)(bF + 1024);
    short8 b3 = *(const short8*)(bF + 1536);

    acc[0][0] = __builtin_amdgcn_mfma_f32_16x16x32_bf16(a0, b0, acc[0][0], 0, 0, 0);
    acc[0][1] = __builtin_amdgcn_mfma_f32_16x16x32_bf16(a0, b1, acc[0][1], 0, 0, 0);
    acc[0][2] = __builtin_amdgcn_mfma_f32_16x16x32_bf16(a0, b2, acc[0][2], 0, 0, 0);
    acc[0][3] = __builtin_amdgcn_mfma_f32_16x16x32_bf16(a0, b3, acc[0][3], 0, 0, 0);
    acc[1][0] = __builtin_amdgcn_mfma_f32_16x16x32_bf16(a1, b0, acc[1][0], 0, 0, 0);
    acc[1][1] = __builtin_amdgcn_mfma_f32_16x16x32_bf16(a1, b1, acc[1][1], 0, 0, 0);
    acc[1][2] = __builtin_amdgcn_mfma_f32_16x16x32_bf16(a1, b2, acc[1][2], 0, 0, 0);
    acc[1][3] = __builtin_amdgcn_mfma_f32_16x16x32_bf16(a1, b3, acc[1][3], 0, 0, 0);
    acc[2][0] = __builtin_amdgcn_mfma_f32_16x16x32_bf16(a2, b0, acc[2][0], 0, 0, 0);
    acc[2][1] = __builtin_amdgcn_mfma_f32_16x16x32_bf16(a2, b1, acc[2][1], 0, 0, 0);
    acc[2][2] = __builtin_amdgcn_mfma_f32_16x16x32_bf16(a2, b2, acc[2][2], 0, 0, 0);
    acc[2][3] = __builtin_amdgcn_mfma_f32_16x16x32_bf16(a2, b3, acc[2][3], 0, 0, 0);
    acc[3][0] = __builtin_amdgcn_mfma_f32_16x16x32_bf16(a3, b0, acc[3][0], 0, 0, 0);
    acc[3][1] = __builtin_amdgcn_mfma_f32_16x16x32_bf16(a3, b1, acc[3][1], 0, 0, 0);
    acc[3][2] = __builtin_amdgcn_mfma_f32_16x16x32_bf16(a3, b2, acc[3][2], 0, 0, 0);
    acc[3][3] = __builtin_amdgcn_mfma_f32_16x16x32_bf16(a3, b3, acc[3][3], 0, 0, 0);

    __syncthreads();   // compiler drains vmcnt+lgkm here -> buf cur^1 ready
    cur ^= 1;
  }
#undef STAGE

  // epilogue
  const int col = lane & 15;
  const int rbase = (lane >> 4) * 4;
#pragma unroll
  for (int ni = 0; ni < 4; ++ni) {
    const unsigned n = (unsigned)(n0 + wn * 64 + ni * 16 + col);
    const unsigned b = n / 4624u;
    const float* dr = dbuf + b * 512;
#pragma unroll
    for (int mi = 0; mi < 4; ++mi) {
      const int ob = o0 + wm * 64 + mi * 16 + rbase;
#pragma unroll
      for (int j = 0; j < 4; ++j) {
        const int o = ob + j;
        float v = acc[mi][ni][j] * dr[o] + convb[o];
        v = fminf(fmaxf(v, -256.f), 256.f);
        ybuf[(size_t)o * NSPAT + n] = v;
      }
    }
  }
}

// ---------------- kernel 8: fused up2 + lrelu + down2, 512 threads, batched LDS reads ----------------
// LDS (floats): uB[66*67]=4422 | uhB[66*138]=9108 | zB[138*138]=19044 ; dhT[64*138]=8832 overlays 0
__global__ __launch_bounds__(512) void updown_kernel(const float* __restrict__ ybuf,
                                                     const float* __restrict__ upf,
                                                     const float* __restrict__ dnf,
                                                     float* __restrict__ out) {
  extern __shared__ float sm[];
  float* uB  = sm;
  float* uhB = sm + 4422;
  float* zB  = sm + 13530;
  float* dhT = sm;          // [64][138] overlay

  const int ch = blockIdx.x;
  const int o = ch & 511, b = ch >> 9;
  const float* ybase = ybuf + (size_t)o * NSPAT + b * PLANE;
  const int t = threadIdx.x;

  float f2[12], g[12];
#pragma unroll
  for (int m = 0; m < 12; ++m) { f2[m] = upf[11 - m] * 2.0f; g[m] = dnf[11 - m]; }

  // P1: load u (66x66) from ybuf (68-stride plane)
  for (int e = t; e < 4356; e += 512) {
    int p = e / 66, q = e - p * 66;
    uB[p * 67 + q] = ybase[p * 68 + q];
  }
  __syncthreads();

  // P2: horizontal upsample. units (p<66, seg<6), e0=seg*12, outputs uh[p][2e],[2e+1]
  if (t < 396) {
    int p = t % 66, seg = t / 66;
    int e0 = seg * 12;
    const float* ur = uB + p * 67;
    float R[17];
#pragma unroll
    for (int i = 0; i < 17; ++i) {
      int c = e0 - 4 + i;
      R[i] = (c >= 0 && c < 66) ? ur[c] : 0.f;
    }
    float* uhr = uhB + p * 138;
#pragma unroll
    for (int m = 0; m < 12; ++m) {
      int e = e0 + m;
      if (e < 69) {
        float ev = f2[1]*R[m] + f2[3]*R[m+1] + f2[5]*R[m+2] + f2[7]*R[m+3] + f2[9]*R[m+4] + f2[11]*R[m+5];
        float od = f2[0]*R[m] + f2[2]*R[m+1] + f2[4]*R[m+2] + f2[6]*R[m+3] + f2[8]*R[m+4] + f2[10]*R[m+5];
        uhr[2 * e]     = ev;
        uhr[2 * e + 1] = od;
      }
    }
  }
  __syncthreads();

  // P3: vertical upsample + lrelu*sqrt2 + clamp. units (c<138, grp<3), e0=grp*23
  if (t < 414) {
    int c = t % 138, grp = t / 138;
    int e0 = grp * 23;
    float R[28];
#pragma unroll
    for (int i = 0; i < 28; ++i) {
      int j = e0 - 4 + i;
      R[i] = (j >= 0 && j < 66) ? uhB[j * 138 + c] : 0.f;
    }
#pragma unroll
    for (int m = 0; m < 23; ++m) {
      int e = e0 + m;
      float ev = f2[1]*R[m] + f2[3]*R[m+1] + f2[5]*R[m+2] + f2[7]*R[m+3] + f2[9]*R[m+4] + f2[11]*R[m+5];
      float od = f2[0]*R[m] + f2[2]*R[m+1] + f2[4]*R[m+2] + f2[6]*R[m+3] + f2[8]*R[m+4] + f2[10]*R[m+5];
      ev = (ev > 0.f ? ev : 0.2f * ev) * 1.4142135623730951f;
      od = (od > 0.f ? od : 0.2f * od) * 1.4142135623730951f;
      ev = fminf(fmaxf(ev, -256.f), 256.f);
      od = fminf(fmaxf(od, -256.f), 256.f);
      zB[(2 * e) * 138 + c]     = ev;
      zB[(2 * e + 1) * 138 + c] = od;
    }
  }
  __syncthreads();

  // P4: horizontal downsample -> dhT[r][tt]. units (tt<138, grp<3), r0=grp*22
  if (t < 414) {
    int tt = t % 138, grp = t / 138;
    int r0 = grp * 22;
    const float* zr = zB + tt * 138;
    float R[54];
#pragma unroll
    for (int i = 0; i < 54; ++i) {
      int c = 2 * r0 + i;
      R[i] = zr[c < 138 ? c : 137];
    }
    float* dcol = dhT + tt;
#pragma unroll
    for (int m = 0; m < 22; ++m) {
      int r = r0 + m;
      if (r < 64) {
        float v = g[0]*R[2*m] + g[1]*R[2*m+1] + g[2]*R[2*m+2] + g[3]*R[2*m+3]
                + g[4]*R[2*m+4] + g[5]*R[2*m+5] + g[6]*R[2*m+6] + g[7]*R[2*m+7]
                + g[8]*R[2*m+8] + g[9]*R[2*m+9] + g[10]*R[2*m+10] + g[11]*R[2*m+11];
        dcol[r * 138] = v;
      }
    }
  }
  __syncthreads();

  // P5: vertical downsample -> out[s][r]. units (r<64, grp<8), s0=grp*8
  {
    int r = t & 63, grp = t >> 6;
    int s0 = grp * 8;
    const float* dr = dhT + r * 138;
    float R[26];
#pragma unroll
    for (int i = 0; i < 26; ++i) R[i] = dr[2 * s0 + i];
    float* ob = out + (((size_t)(b * 512 + o)) << 12) + r;
#pragma unroll
    for (int m = 0; m < 8; ++m) {
      float v = g[0]*R[2*m] + g[1]*R[2*m+1] + g[2]*R[2*m+2] + g[3]*R[2*m+3]
              + g[4]*R[2*m+4] + g[5]*R[2*m+5] + g[6]*R[2*m+6] + g[7]*R[2*m+7]
              + g[8]*R[2*m+8] + g[9]*R[2*m+9] + g[10]*R[2*m+10] + g[11]*R[2*m+11];
      ob[(size_t)(s0 + m) * 64] = v;
    }
  }
}

// ---------------- launcher ----------------
extern "C" void kernel_launch(void* const* d_in, const int* in_sizes, int n_in,
                              void* d_out, int out_size, void* d_ws, size_t ws_size,
                              hipStream_t stream) {
  const float* x     = (const float*)d_in[0];
  const float* w_lat = (const float*)d_in[1];
  const float* convw = (const float*)d_in[2];
  const float* convb = (const float*)d_in[3];
  const float* affw  = (const float*)d_in[4];
  const float* affb  = (const float*)d_in[5];
  const float* upf   = (const float*)d_in[6];
  const float* dnf   = (const float*)d_in[7];
  float* out = (float*)d_out;

  char* ws = (char*)d_ws;
  float* s         = (float*)(ws + 0);
  float* s2        = (float*)(ws + 16384);
  float* rowscale  = (float*)(ws + 32768);
  float* W2        = (float*)(ws + 34816);
  float* dbuf      = (float*)(ws + 1083392);
  unsigned short* wbf = (unsigned short*)(ws + 1099776);
  unsigned short* xhp = (unsigned short*)(ws + 5818368);
  float* ybuf      = (float*)(ws + 43862016);

  styles_kernel<<<16, 256, 0, stream>>>(w_lat, affw, affb, s);
  norm_kernel<<<1, 256, 0, stream>>>(s, s2);
  rowscale_kernel<<<512, 256, 0, stream>>>(convw, rowscale);
  wprep_kernel<<<512, 256, 0, stream>>>(convw, rowscale, wbf, W2);
  demod_kernel<<<16, 256, 0, stream>>>(s2, W2, dbuf);

  hipMemsetAsync(xhp, 0, (size_t)XHP_ROWS * 512 * 2, stream);
  xprep_kernel<<<512, 256, 0, stream>>>(x, s, xhp);

  dim3 cgrid(289, 4);
  conv_kernel<<<cgrid, 256, 0, stream>>>(wbf, xhp, dbuf, convb, ybuf);

  updown_kernel<<<4096, 512, 130296, stream>>>(ybuf, upf, dnf, out);
}

// Round 3
// 463.840 us; speedup vs baseline: 1.3429x; 1.0153x over previous
//
#include <hip/hip_runtime.h>
#include <stdint.h>

// ---------------- types / helpers ----------------
typedef short short8 __attribute__((ext_vector_type(8)));
typedef float f32x4 __attribute__((ext_vector_type(4)));

__device__ __forceinline__ unsigned short f2bf(float f) {
  union { float f; unsigned u; } v; v.f = f;
  unsigned u = v.u;
  u += 0x7fffu + ((u >> 16) & 1u);   // RNE
  return (unsigned short)(u >> 16);
}

__device__ __forceinline__ void gl16(const void* g, void* l) {
  __builtin_amdgcn_global_load_lds(
      (__attribute__((address_space(1))) void*)(uintptr_t)g,
      (__attribute__((address_space(3))) void*)l, 16, 0, 0);
}

// Problem constants
// B=8 CIN=512 COUT=512 H=W=64, K=3, pad=2 -> conv out 66x66
// padded spatial grid 68x68 per image: N = 8*68*68 = 36992
#define NSPAT 36992
#define PLANE 4624        // 68*68
#define XHP_ROWS 37152    // NSPAT + 160 margin rows

// ---------------- kernel 1: styles = w_lat @ aff_w^T / sqrt(512) + aff_b ----------------
__global__ void styles_kernel(const float* __restrict__ w_lat, const float* __restrict__ affw,
                              const float* __restrict__ affb, float* __restrict__ s) {
  int g = blockIdx.x * 256 + threadIdx.x;   // 0..4095
  int b = g >> 9, i = g & 511;
  const float4* wl = (const float4*)(w_lat + b * 512);
  const float4* aw = (const float4*)(affw + (size_t)i * 512);
  float acc = 0.f;
#pragma unroll 4
  for (int j = 0; j < 128; ++j) {
    float4 a = wl[j], c = aw[j];
    acc += a.x * c.x + a.y * c.y + a.z * c.z + a.w * c.w;
  }
  s[g] = acc * 0.044194173824159216f + affb[i];
}

// ---------------- kernel 2: global normalize s, write s and s2 ----------------
__global__ void norm_kernel(float* __restrict__ s, float* __restrict__ s2) {
  __shared__ float red[256];
  int t = threadIdx.x;
  float acc = 0.f;
  for (int e = t; e < 4096; e += 256) { float v = s[e]; acc += v * v; }
  red[t] = acc; __syncthreads();
  for (int st = 128; st > 0; st >>= 1) {
    if (t < st) red[t] += red[t + st];
    __syncthreads();
  }
  float alpha = rsqrtf(red[0] * (1.0f / 4096.0f));
  for (int e = t; e < 4096; e += 256) {
    float v = s[e] * alpha;
    s[e] = v; s2[e] = v * v;
  }
}

// ---------------- kernel 3: per-output-channel weight scale ----------------
__global__ void rowscale_kernel(const float* __restrict__ convw, float* __restrict__ rowscale) {
  int o = blockIdx.x, t = threadIdx.x;
  const float* wr = convw + (size_t)o * 4608;
  float acc = 0.f;
  for (int e = t; e < 4608; e += 256) { float v = wr[e]; acc += v * v; }
  __shared__ float red[256];
  red[t] = acc; __syncthreads();
  for (int st = 128; st > 0; st >>= 1) {
    if (t < st) red[t] += red[t + st];
    __syncthreads();
  }
  if (t == 0) rowscale[o] = rsqrtf(red[0] * (1.0f / 4608.0f));
}

// ---------------- kernel 4: build bf16 weights (tap, o, i) + W2[o][i] ----------------
__global__ void wprep_kernel(const float* __restrict__ convw, const float* __restrict__ rowscale,
                             unsigned short* __restrict__ wbf, float* __restrict__ W2) {
  int o = blockIdx.x, t = threadIdx.x;
  float sc = rowscale[o];
  for (int i = t; i < 512; i += 256) {
    const float* wp = convw + ((size_t)o * 512 + i) * 9;
    float w9[9]; float ss = 0.f;
#pragma unroll
    for (int m = 0; m < 9; ++m) { float v = wp[m] * sc; w9[m] = v; ss += v * v; }
    W2[((size_t)o << 9) + i] = ss;
#pragma unroll
    for (int m = 0; m < 9; ++m)
      wbf[(((size_t)m * 512 + o) << 9) + i] = f2bf(w9[m]);
  }
}

// ---------------- kernel 5: demod d[b][o] ----------------
__global__ void demod_kernel(const float* __restrict__ s2, const float* __restrict__ W2,
                             float* __restrict__ dbuf) {
  int g = blockIdx.x * 256 + threadIdx.x;  // b*512+o
  int b = g >> 9, o = g & 511;
  const float4* sp = (const float4*)(s2 + b * 512);
  const float4* wp = (const float4*)(W2 + (size_t)o * 512);
  float acc = 1e-8f;
#pragma unroll 4
  for (int j = 0; j < 128; ++j) {
    float4 a = sp[j], c = wp[j];
    acc += a.x * c.x + a.y * c.y + a.z * c.z + a.w * c.w;
  }
  dbuf[g] = rsqrtf(acc);
}

// ---------------- kernel 6: x-hat NHWC padded bf16 : xhp[b][h+2][w+2][i] = bf16(x*s) ----------------
__global__ void xprep_kernel(const float* __restrict__ x, const float* __restrict__ s,
                             unsigned short* __restrict__ xhp) {
  int b = blockIdx.x >> 6, h = blockIdx.x & 63;
  int t = threadIdx.x;
  __shared__ float tile[64 * 65];
  __shared__ float sv[64];
  for (int it = 0; it < 8; ++it) {
    int i0 = it * 64;
    {
      int ii = t >> 2, wseg = (t & 3) * 16;
      const float4* src = (const float4*)(x + (((size_t)(b * 512 + i0 + ii) * 64 + h) << 6) + wseg);
      float4 v0 = src[0], v1 = src[1], v2 = src[2], v3 = src[3];
      float* dst = tile + ii * 65 + wseg;
      dst[0]=v0.x; dst[1]=v0.y; dst[2]=v0.z; dst[3]=v0.w;
      dst[4]=v1.x; dst[5]=v1.y; dst[6]=v1.z; dst[7]=v1.w;
      dst[8]=v2.x; dst[9]=v2.y; dst[10]=v2.z; dst[11]=v2.w;
      dst[12]=v3.x; dst[13]=v3.y; dst[14]=v3.z; dst[15]=v3.w;
    }
    if (t < 64) sv[t] = s[b * 512 + i0 + t];
    __syncthreads();
    {
      int w = t >> 2, ic = (t & 3) * 16;
      alignas(16) unsigned short tmp[16];
#pragma unroll
      for (int k = 0; k < 16; ++k)
        tmp[k] = f2bf(tile[(ic + k) * 65 + w] * sv[ic + k]);
      unsigned short* dst = xhp + ((size_t)b * PLANE + (h + 2) * 68 + (w + 2)) * 512 + i0 + ic;
      *(short8*)dst = *(const short8*)tmp;
      *(short8*)(dst + 8) = *(const short8*)(tmp + 8);
    }
    __syncthreads();
  }
}

// ---------------- kernel 7: implicit-GEMM conv, 128x128 tile ----------------
// 3-deep counted-vmcnt pipeline (T4) + XOR LDS swizzle (T2, both-sides per rule #21)
// A = wbf (tap,o,i), B = xhp NHWC padded; epilogue: *d[b,o] + bias[o], clamp +-256
__global__ __launch_bounds__(256, 3) void conv_kernel(const unsigned short* __restrict__ wbf,
                                                      const unsigned short* __restrict__ xhp,
                                                      const float* __restrict__ dbuf,
                                                      const float* __restrict__ convb,
                                                      float* __restrict__ ybuf) {
  __shared__ unsigned short lds[24576];  // 3 bufs x (A 4096 + B 4096) shorts = 48 KB
  const int t = threadIdx.x;
  const int lane = t & 63, wid = t >> 6;

  // n-major order + bijective XCD chunking: orig = ntile*4 + otile
  int orig = blockIdx.y * 4 + blockIdx.x;
  int xcd = orig & 7, idx = orig >> 3;
  int wg = (xcd < 4) ? (xcd * 145 + idx) : (580 + (xcd - 4) * 144 + idx);
  const int n0 = (wg >> 2) * 128, o0 = (wg & 3) * 128;
  const int wm = wid >> 1, wn = wid & 1;

  // --- staging: lane l loads global quarter q = (l&3) ^ ((l>>3)&3) of its row ---
  const unsigned kc = (((unsigned)(lane & 3)) ^ ((unsigned)(lane >> 3) & 3u)) * 8u;
  const unsigned aOff0 = (unsigned)(o0 + wid * 32 + (lane >> 2)) * 512 + kc;
  const unsigned aOff1 = aOff0 + 16 * 512;
  const unsigned bOff0 = (unsigned)(n0 + wid * 32 + (lane >> 2)) * 512 + kc;
  const unsigned bOff1 = bOff0 + 16 * 512;

  // --- frag read offsets: row r=lane&15, phys quarter = (lane>>4) ^ ((r>>1)&3) ---
  const unsigned xq = ((unsigned)(lane >> 4)) ^ (((unsigned)(lane & 15) >> 1) & 3u);
  const unsigned aFo = wm * 2048 + (lane & 15) * 32 + xq * 8;
  const unsigned bFo = 4096 + wn * 2048 + (lane & 15) * 32 + xq * 8;

  f32x4 acc[4][4] = {};

#define STAGE(stp, off) do {                                           \
    const unsigned tp = (unsigned)(stp) >> 4;                          \
    const unsigned k0 = ((unsigned)(stp) & 15u) * 32u;                 \
    const unsigned aT = tp * 262144u + k0;                             \
    const unsigned bS = ((tp / 3u) * 68u + (tp % 3u)) * 512u + k0;     \
    unsigned short* la = lds + (off) + wid * 1024;                     \
    unsigned short* lb = lds + (off) + 4096 + wid * 1024;              \
    gl16(wbf + aT + aOff0, la);                                        \
    gl16(wbf + aT + aOff1, la + 512);                                  \
    gl16(xhp + bS + bOff0, lb);                                        \
    gl16(xhp + bS + bOff1, lb + 512);                                  \
  } while (0)

#define COMPUTE(rdoff) do {                                            \
    const unsigned short* aF = lds + (rdoff) + aFo;                    \
    const unsigned short* bF = lds + (rdoff) + bFo;                    \
    short8 a0 = *(const short8*)(aF + 0);                              \
    short8 a1 = *(const short8*)(aF + 512);                            \
    short8 a2 = *(const short8*)(aF + 1024);                           \
    short8 a3 = *(const short8*)(aF + 1536);                           \
    short8 b0 = *(const short8*)(bF + 0);                              \
    short8 b1 = *(const short8*)(bF + 512);                            \
    short8 b2 = *(const short8*)(bF + 1024);                           \
    short8 b3 = *(const short8*)(bF + 1536);                           \
    acc[0][0] = __builtin_amdgcn_mfma_f32_16x16x32_bf16(a0, b0, acc[0][0], 0, 0, 0); \
    acc[0][1] = __builtin_amdgcn_mfma_f32_16x16x32_bf16(a0, b1, acc[0][1], 0, 0, 0); \
    acc[0][2] = __builtin_amdgcn_mfma_f32_16x16x32_bf16(a0, b2, acc[0][2], 0, 0, 0); \
    acc[0][3] = __builtin_amdgcn_mfma_f32_16x16x32_bf16(a0, b3, acc[0][3], 0, 0, 0); \
    acc[1][0] = __builtin_amdgcn_mfma_f32_16x16x32_bf16(a1, b0, acc[1][0], 0, 0, 0); \
    acc[1][1] = __builtin_amdgcn_mfma_f32_16x16x32_bf16(a1, b1, acc[1][1], 0, 0, 0); \
    acc[1][2] = __builtin_amdgcn_mfma_f32_16x16x32_bf16(a1, b2, acc[1][2], 0, 0, 0); \
    acc[1][3] = __builtin_amdgcn_mfma_f32_16x16x32_bf16(a1, b3, acc[1][3], 0, 0, 0); \
    acc[2][0] = __builtin_amdgcn_mfma_f32_16x16x32_bf16(a2, b0, acc[2][0], 0, 0, 0); \
    acc[2][1] = __builtin_amdgcn_mfma_f32_16x16x32_bf16(a2, b1, acc[2][1], 0, 0, 0); \
    acc[2][2] = __builtin_amdgcn_mfma_f32_16x16x32_bf16(a2, b2, acc[2][2], 0, 0, 0); \
    acc[2][3] = __builtin_amdgcn_mfma_f32_16x16x32_bf16(a2, b3, acc[2][3], 0, 0, 0); \
    acc[3][0] = __builtin_amdgcn_mfma_f32_16x16x32_bf16(a3, b0, acc[3][0], 0, 0, 0); \
    acc[3][1] = __builtin_amdgcn_mfma_f32_16x16x32_bf16(a3, b1, acc[3][1], 0, 0, 0); \
    acc[3][2] = __builtin_amdgcn_mfma_f32_16x16x32_bf16(a3, b2, acc[3][2], 0, 0, 0); \
    acc[3][3] = __builtin_amdgcn_mfma_f32_16x16x32_bf16(a3, b3, acc[3][3], 0, 0, 0); \
  } while (0)

  STAGE(0, 0u);
  STAGE(1, 8192u);

  unsigned rd = 0, wr2 = 16384;
  for (int step = 0; step < 143; ++step) {
    // wait for oldest 4 loads (buf rd) only; keep next buf's 4 in flight
    asm volatile("s_waitcnt vmcnt(4)" ::: "memory");
    __builtin_amdgcn_s_barrier();
    asm volatile("" ::: "memory");
    if (step < 142) STAGE(step + 2, wr2);
    COMPUTE(rd);
    asm volatile("" ::: "memory");
    rd += 8192;  if (rd == 24576) rd = 0;
    wr2 += 8192; if (wr2 == 24576) wr2 = 0;
  }
  asm volatile("s_waitcnt vmcnt(0)" ::: "memory");
  __builtin_amdgcn_s_barrier();
  asm volatile("" ::: "memory");
  COMPUTE(rd);
#undef STAGE
#undef COMPUTE

  // epilogue
  const int col = lane & 15;
  const int rbase = (lane >> 4) * 4;
#pragma unroll
  for (int ni = 0; ni < 4; ++ni) {
    const unsigned n = (unsigned)(n0 + wn * 64 + ni * 16 + col);
    const unsigned b = n / 4624u;
    const float* dr = dbuf + b * 512;
#pragma unroll
    for (int mi = 0; mi < 4; ++mi) {
      const int ob = o0 + wm * 64 + mi * 16 + rbase;
#pragma unroll
      for (int j = 0; j < 4; ++j) {
        const int o = ob + j;
        float v = acc[mi][ni][j] * dr[o] + convb[o];
        v = fminf(fmaxf(v, -256.f), 256.f);
        ybuf[(size_t)o * NSPAT + n] = v;
      }
    }
  }
}

// ---------------- kernel 8: fused up2 + lrelu + down2 ----------------
// 2 blocks per channel (column halves) -> 72.5 KB LDS -> 2 blocks/CU; flat unit-grids, all lanes active.
// half h: output cols r in [h*32, h*32+32); u cols [h*27, +39); z/uh cols [h*63, +75)
__global__ __launch_bounds__(512) void updown_kernel(const float* __restrict__ ybuf,
                                                     const float* __restrict__ upf,
                                                     const float* __restrict__ dnf,
                                                     float* __restrict__ out) {
  extern __shared__ float sm[];
  float* uB  = sm;            // [66][40]
  float* uhB = sm + 2640;     // [66][76]
  float* zB  = sm + 7656;     // [138][76]  (ends 18144)
  float* dhT = sm;            // [138][33] overlay (valid after P3)

  const int blk = blockIdx.x;
  const int half = blk & 1, ch = blk >> 1;
  const int o = ch & 511, b = ch >> 9;
  const float* ybase = ybuf + (size_t)o * NSPAT + b * PLANE;
  const int t = threadIdx.x;

  const int ub0 = half * 27, zc0 = half * 63, e0b = half * 31;

  float f2[12], g[12];
#pragma unroll
  for (int m = 0; m < 12; ++m) { f2[m] = upf[11 - m] * 2.0f; g[m] = dnf[11 - m]; }

  // P1: load u window 66 x 39
  for (int e = t; e < 2574; e += 512) {
    int p = e / 39, q = e - p * 39;
    uB[p * 40 + q] = ybase[p * 68 + ub0 + q];
  }
  __syncthreads();

  // P2: horizontal upsample. units (p<66, ei<38), e = e0b+ei
  for (int u = t; u < 2508; u += 512) {
    int p = u / 38, ei = u - p * 38;
    int e = e0b + ei;
    const float* ur = uB + p * 40;
    float w[6];
#pragma unroll
    for (int r = 0; r < 6; ++r) {
      int j = e - 4 + r;
      w[r] = (j >= 0 && j < 66) ? ur[j - ub0] : 0.f;
    }
    float ev = f2[1]*w[0] + f2[3]*w[1] + f2[5]*w[2] + f2[7]*w[3] + f2[9]*w[4] + f2[11]*w[5];
    float od = f2[0]*w[0] + f2[2]*w[1] + f2[4]*w[2] + f2[6]*w[3] + f2[8]*w[4] + f2[10]*w[5];
    int c0 = 2 * e - zc0;
    float* uhr = uhB + p * 76;
    if (c0 >= 0 && c0 < 75) uhr[c0] = ev;
    if (c0 + 1 >= 0 && c0 + 1 < 75) uhr[c0 + 1] = od;
  }
  __syncthreads();

  // P3: vertical upsample + lrelu*sqrt2 + clamp. units (e<69, cl<75)
  for (int u = t; u < 5175; u += 512) {
    int e = u / 75, cl = u - e * 75;
    float w[6];
#pragma unroll
    for (int r = 0; r < 6; ++r) {
      int j = e - 4 + r;
      w[r] = (j >= 0 && j < 66) ? uhB[j * 76 + cl] : 0.f;
    }
    float ev = f2[1]*w[0] + f2[3]*w[1] + f2[5]*w[2] + f2[7]*w[3] + f2[9]*w[4] + f2[11]*w[5];
    float od = f2[0]*w[0] + f2[2]*w[1] + f2[4]*w[2] + f2[6]*w[3] + f2[8]*w[4] + f2[10]*w[5];
    ev = (ev > 0.f ? ev : 0.2f * ev) * 1.4142135623730951f;
    od = (od > 0.f ? od : 0.2f * od) * 1.4142135623730951f;
    ev = fminf(fmaxf(ev, -256.f), 256.f);
    od = fminf(fmaxf(od, -256.f), 256.f);
    zB[(2 * e) * 76 + cl]     = ev;
    zB[(2 * e + 1) * 76 + cl] = od;
  }
  __syncthreads();

  // P4: horizontal downsample -> dhT[tt][ri]. units (tt<138, ri<32); global r = half*32+ri
  for (int u = t; u < 4416; u += 512) {
    int tt = u >> 5, ri = u & 31;
    int r = half * 32 + ri;
    const float* zr = zB + tt * 76 + (2 * r - zc0);
    float v = g[0]*zr[0] + g[1]*zr[1] + g[2]*zr[2] + g[3]*zr[3] + g[4]*zr[4] + g[5]*zr[5]
            + g[6]*zr[6] + g[7]*zr[7] + g[8]*zr[8] + g[9]*zr[9] + g[10]*zr[10] + g[11]*zr[11];
    dhT[tt * 33 + ri] = v;
  }
  __syncthreads();

  // P5: vertical downsample -> out. units (s<64, ri<32)
  for (int u = t; u < 2048; u += 512) {
    int s = u >> 5, ri = u & 31;
    const float* dc = dhT + ri;
    float v = g[0]*dc[(2*s+0)*33] + g[1]*dc[(2*s+1)*33] + g[2]*dc[(2*s+2)*33] + g[3]*dc[(2*s+3)*33]
            + g[4]*dc[(2*s+4)*33] + g[5]*dc[(2*s+5)*33] + g[6]*dc[(2*s+6)*33] + g[7]*dc[(2*s+7)*33]
            + g[8]*dc[(2*s+8)*33] + g[9]*dc[(2*s+9)*33] + g[10]*dc[(2*s+10)*33] + g[11]*dc[(2*s+11)*33];
    out[(((size_t)(b * 512 + o)) << 12) + s * 64 + half * 32 + ri] = v;
  }
}

// ---------------- launcher ----------------
extern "C" void kernel_launch(void* const* d_in, const int* in_sizes, int n_in,
                              void* d_out, int out_size, void* d_ws, size_t ws_size,
                              hipStream_t stream) {
  const float* x     = (const float*)d_in[0];
  const float* w_lat = (const float*)d_in[1];
  const float* convw = (const float*)d_in[2];
  const float* convb = (const float*)d_in[3];
  const float* affw  = (const float*)d_in[4];
  const float* affb  = (const float*)d_in[5];
  const float* upf   = (const float*)d_in[6];
  const float* dnf   = (const float*)d_in[7];
  float* out = (float*)d_out;

  char* ws = (char*)d_ws;
  float* s         = (float*)(ws + 0);
  float* s2        = (float*)(ws + 16384);
  float* rowscale  = (float*)(ws + 32768);
  float* W2        = (float*)(ws + 34816);
  float* dbuf      = (float*)(ws + 1083392);
  unsigned short* wbf = (unsigned short*)(ws + 1099776);
  unsigned short* xhp = (unsigned short*)(ws + 5818368);
  float* ybuf      = (float*)(ws + 43862016);

  styles_kernel<<<16, 256, 0, stream>>>(w_lat, affw, affb, s);
  norm_kernel<<<1, 256, 0, stream>>>(s, s2);
  rowscale_kernel<<<512, 256, 0, stream>>>(convw, rowscale);
  wprep_kernel<<<512, 256, 0, stream>>>(convw, rowscale, wbf, W2);
  demod_kernel<<<16, 256, 0, stream>>>(s2, W2, dbuf);

  hipMemsetAsync(xhp, 0, (size_t)XHP_ROWS * 512 * 2, stream);
  xprep_kernel<<<512, 256, 0, stream>>>(x, s, xhp);

  dim3 cgrid(4, 289);
  conv_kernel<<<cgrid, 256, 0, stream>>>(wbf, xhp, dbuf, convb, ybuf);

  updown_kernel<<<8192, 512, 72576, stream>>>(ybuf, upf, dnf, out);
}

// Round 4
// 426.674 us; speedup vs baseline: 1.4598x; 1.0871x over previous
//
#include <hip/hip_runtime.h>
#include <stdint.h>

// ---------------- types / helpers ----------------
typedef short short8 __attribute__((ext_vector_type(8)));
typedef float f32x4 __attribute__((ext_vector_type(4)));

__device__ __forceinline__ unsigned short f2bf(float f) {
  union { float f; unsigned u; } v; v.f = f;
  unsigned u = v.u;
  u += 0x7fffu + ((u >> 16) & 1u);   // RNE
  return (unsigned short)(u >> 16);
}

__device__ __forceinline__ void gl16(const void* g, void* l) {
  __builtin_amdgcn_global_load_lds(
      (__attribute__((address_space(1))) void*)(uintptr_t)g,
      (__attribute__((address_space(3))) void*)l, 16, 0, 0);
}

// Problem constants
#define NSPAT 36992
#define PLANE 4624        // 68*68
#define XHP_ROWS 37152    // NSPAT + margin rows

// ---------------- kernel 1: styles ----------------
__global__ void styles_kernel(const float* __restrict__ w_lat, const float* __restrict__ affw,
                              const float* __restrict__ affb, float* __restrict__ s) {
  int g = blockIdx.x * 256 + threadIdx.x;   // 0..4095
  int b = g >> 9, i = g & 511;
  const float4* wl = (const float4*)(w_lat + b * 512);
  const float4* aw = (const float4*)(affw + (size_t)i * 512);
  float acc = 0.f;
#pragma unroll 4
  for (int j = 0; j < 128; ++j) {
    float4 a = wl[j], c = aw[j];
    acc += a.x * c.x + a.y * c.y + a.z * c.z + a.w * c.w;
  }
  s[g] = acc * 0.044194173824159216f + affb[i];
}

// ---------------- kernel 2: global normalize s ----------------
__global__ void norm_kernel(float* __restrict__ s, float* __restrict__ s2) {
  __shared__ float red[256];
  int t = threadIdx.x;
  float acc = 0.f;
  for (int e = t; e < 4096; e += 256) { float v = s[e]; acc += v * v; }
  red[t] = acc; __syncthreads();
  for (int st = 128; st > 0; st >>= 1) {
    if (t < st) red[t] += red[t + st];
    __syncthreads();
  }
  float alpha = rsqrtf(red[0] * (1.0f / 4096.0f));
  for (int e = t; e < 4096; e += 256) {
    float v = s[e] * alpha;
    s[e] = v; s2[e] = v * v;
  }
}

// ---------------- kernel 3: per-output-channel weight scale ----------------
__global__ void rowscale_kernel(const float* __restrict__ convw, float* __restrict__ rowscale) {
  int o = blockIdx.x, t = threadIdx.x;
  const float* wr = convw + (size_t)o * 4608;
  float acc = 0.f;
  for (int e = t; e < 4608; e += 256) { float v = wr[e]; acc += v * v; }
  __shared__ float red[256];
  red[t] = acc; __syncthreads();
  for (int st = 128; st > 0; st >>= 1) {
    if (t < st) red[t] += red[t + st];
    __syncthreads();
  }
  if (t == 0) rowscale[o] = rsqrtf(red[0] * (1.0f / 4608.0f));
}

// ---------------- kernel 4: bf16 weights (tap, o, i) + W2 ----------------
__global__ void wprep_kernel(const float* __restrict__ convw, const float* __restrict__ rowscale,
                             unsigned short* __restrict__ wbf, float* __restrict__ W2) {
  int o = blockIdx.x, t = threadIdx.x;
  float sc = rowscale[o];
  for (int i = t; i < 512; i += 256) {
    const float* wp = convw + ((size_t)o * 512 + i) * 9;
    float w9[9]; float ss = 0.f;
#pragma unroll
    for (int m = 0; m < 9; ++m) { float v = wp[m] * sc; w9[m] = v; ss += v * v; }
    W2[((size_t)o << 9) + i] = ss;
#pragma unroll
    for (int m = 0; m < 9; ++m)
      wbf[(((size_t)m * 512 + o) << 9) + i] = f2bf(w9[m]);
  }
}

// ---------------- kernel 5: demod ----------------
__global__ void demod_kernel(const float* __restrict__ s2, const float* __restrict__ W2,
                             float* __restrict__ dbuf) {
  int g = blockIdx.x * 256 + threadIdx.x;
  int b = g >> 9, o = g & 511;
  const float4* sp = (const float4*)(s2 + b * 512);
  const float4* wp = (const float4*)(W2 + (size_t)o * 512);
  float acc = 1e-8f;
#pragma unroll 4
  for (int j = 0; j < 128; ++j) {
    float4 a = sp[j], c = wp[j];
    acc += a.x * c.x + a.y * c.y + a.z * c.z + a.w * c.w;
  }
  dbuf[g] = rsqrtf(acc);
}

// ---------------- kernel 6: x-hat NHWC padded bf16 ----------------
__global__ void xprep_kernel(const float* __restrict__ x, const float* __restrict__ s,
                             unsigned short* __restrict__ xhp) {
  int b = blockIdx.x >> 6, h = blockIdx.x & 63;
  int t = threadIdx.x;
  __shared__ float tile[64 * 65];
  __shared__ float sv[64];
  for (int it = 0; it < 8; ++it) {
    int i0 = it * 64;
    {
      int ii = t >> 2, wseg = (t & 3) * 16;
      const float4* src = (const float4*)(x + (((size_t)(b * 512 + i0 + ii) * 64 + h) << 6) + wseg);
      float4 v0 = src[0], v1 = src[1], v2 = src[2], v3 = src[3];
      float* dst = tile + ii * 65 + wseg;
      dst[0]=v0.x; dst[1]=v0.y; dst[2]=v0.z; dst[3]=v0.w;
      dst[4]=v1.x; dst[5]=v1.y; dst[6]=v1.z; dst[7]=v1.w;
      dst[8]=v2.x; dst[9]=v2.y; dst[10]=v2.z; dst[11]=v2.w;
      dst[12]=v3.x; dst[13]=v3.y; dst[14]=v3.z; dst[15]=v3.w;
    }
    if (t < 64) sv[t] = s[b * 512 + i0 + t];
    __syncthreads();
    {
      int w = t >> 2, ic = (t & 3) * 16;
      alignas(16) unsigned short tmp[16];
#pragma unroll
      for (int k = 0; k < 16; ++k)
        tmp[k] = f2bf(tile[(ic + k) * 65 + w] * sv[ic + k]);
      unsigned short* dst = xhp + ((size_t)b * PLANE + (h + 2) * 68 + (w + 2)) * 512 + i0 + ic;
      *(short8*)dst = *(const short8*)tmp;
      *(short8*)(dst + 8) = *(const short8*)(tmp + 8);
    }
    __syncthreads();
  }
}

// ---------------- kernel 7: implicit-GEMM conv, 256x128 block, wave=128m x 64n ----------------
// 3-deep counted-vmcnt pipeline; sigma LDS swizzle (verified 0 conflicts in R3)
__global__ __launch_bounds__(256, 2) void conv_kernel(const unsigned short* __restrict__ wbf,
                                                      const unsigned short* __restrict__ xhp,
                                                      const float* __restrict__ dbuf,
                                                      const float* __restrict__ convb,
                                                      float* __restrict__ ybuf) {
  extern __shared__ unsigned short lds[];  // 3 bufs x (A 8192 + B 4096) shorts = 72 KB
  const int t = threadIdx.x;
  const int lane = t & 63, wid = t >> 6;

  // o-major order + bijective XCD chunking: orig = otile*289 + ntile; nwg=578, q=72, r=2
  int orig = blockIdx.y * 2 + blockIdx.x;          // just a flat id 0..577
  int xcd = orig & 7, idx = orig >> 3;
  int wg = (xcd < 2) ? (xcd * 73 + idx) : (146 + (xcd - 2) * 72 + idx);
  const int o0 = (wg / 289) * 256, n0 = (wg % 289) * 128;
  const int wm = wid >> 1, wn = wid & 1;

  // staging: lane l stages global quarter q=(l&3)^((l>>3)&3) of row (chunkbase + (l>>2))
  const unsigned kc = (((unsigned)(lane & 3)) ^ ((unsigned)(lane >> 3) & 3u)) * 8u;
  const unsigned aOff0 = (unsigned)(o0 + wid * 64 + (lane >> 2)) * 512 + kc;  // +c*8192, c<4
  const unsigned bOff0 = (unsigned)(n0 + wid * 32 + (lane >> 2)) * 512 + kc;  // +c*8192, c<2

  // frag read: row r=lane&15, phys quarter = (lane>>4) ^ ((r>>1)&3)
  const unsigned xq = ((unsigned)(lane >> 4)) ^ (((unsigned)(lane & 15) >> 1) & 3u);
  const unsigned aFo = (unsigned)(wm * 128 + (lane & 15)) * 32 + xq * 8;          // + mi*512
  const unsigned bFo = 8192u + (unsigned)(wn * 64 + (lane & 15)) * 32 + xq * 8;   // + ni*512

  f32x4 acc[8][4] = {};

#define STAGE(stp, off) do {                                           \
    const unsigned tp = (unsigned)(stp) >> 4;                          \
    const unsigned k0 = ((unsigned)(stp) & 15u) * 32u;                 \
    const unsigned aT = tp * 262144u + k0;                             \
    const unsigned bS = ((tp / 3u) * 68u + (tp % 3u)) * 512u + k0;     \
    unsigned short* la = lds + (off) + wid * 2048;                     \
    unsigned short* lb = lds + (off) + 8192 + wid * 1024;              \
    gl16(wbf + aT + aOff0,          la);                               \
    gl16(wbf + aT + aOff0 + 8192,   la + 512);                         \
    gl16(wbf + aT + aOff0 + 16384,  la + 1024);                        \
    gl16(wbf + aT + aOff0 + 24576,  la + 1536);                        \
    gl16(xhp + bS + bOff0,          lb);                               \
    gl16(xhp + bS + bOff0 + 8192,   lb + 512);                         \
  } while (0)

#define COMPUTE(rdoff) do {                                            \
    const unsigned short* aF = lds + (rdoff) + aFo;                    \
    const unsigned short* bF = lds + (rdoff) + bFo;                    \
    short8 bfr[4];                                                     \
    _Pragma("unroll")                                                  \
    for (int ni = 0; ni < 4; ++ni) bfr[ni] = *(const short8*)(bF + ni * 512); \
    _Pragma("unroll")                                                  \
    for (int mi = 0; mi < 8; ++mi) {                                   \
      short8 afr = *(const short8*)(aF + mi * 512);                    \
      _Pragma("unroll")                                                \
      for (int ni = 0; ni < 4; ++ni)                                   \
        acc[mi][ni] = __builtin_amdgcn_mfma_f32_16x16x32_bf16(afr, bfr[ni], acc[mi][ni], 0, 0, 0); \
    }                                                                  \
  } while (0)

  STAGE(0, 0u);
  STAGE(1, 12288u);

  unsigned rd = 0, wr2 = 24576;
  for (int step = 0; step < 143; ++step) {
    asm volatile("s_waitcnt vmcnt(6)" ::: "memory");   // oldest stage's 6 loads done
    __builtin_amdgcn_s_barrier();
    if (step < 142) STAGE(step + 2, wr2);
    COMPUTE(rd);
    rd += 12288;  if (rd == 36864) rd = 0;
    wr2 += 12288; if (wr2 == 36864) wr2 = 0;
  }
  asm volatile("s_waitcnt vmcnt(0)" ::: "memory");
  __builtin_amdgcn_s_barrier();
  COMPUTE(rd);
#undef STAGE
#undef COMPUTE

  // epilogue
  const int col = lane & 15;
  const int rbase = (lane >> 4) * 4;
#pragma unroll
  for (int ni = 0; ni < 4; ++ni) {
    const unsigned n = (unsigned)(n0 + wn * 64 + ni * 16 + col);
    const unsigned b = n / 4624u;
    const float* dr = dbuf + b * 512;
#pragma unroll
    for (int mi = 0; mi < 8; ++mi) {
      const int ob = o0 + wm * 128 + mi * 16 + rbase;
#pragma unroll
      for (int j = 0; j < 4; ++j) {
        const int o = ob + j;
        float v = acc[mi][ni][j] * dr[o] + convb[o];
        v = fminf(fmaxf(v, -256.f), 256.f);
        ybuf[(size_t)o * NSPAT + n] = v;
      }
    }
  }
}

// ---------------- kernel 8: fused up2 + lrelu + down2, float4-vectorized LDS ----------------
// 2 blocks per channel (output col halves [0..31],[32..63]); window starts at 64*half
// LDS floats: uB[66][44]=2904 | uhB[66][76]=5016 | zB[138][76]=10488 (total 18408 = 73632 B)
// dhT[138][36]=4968 overlays uB/uhB after P3.
__device__ __forceinline__ f32x4 lrelu_clamp4(f32x4 v) {
  f32x4 r;
#pragma unroll
  for (int i = 0; i < 4; ++i) {
    float x = v[i];
    x = (x > 0.f ? x : 0.2f * x) * 1.4142135623730951f;
    r[i] = fminf(fmaxf(x, -256.f), 256.f);
  }
  return r;
}

__global__ __launch_bounds__(512) void updown_kernel(const float* __restrict__ ybuf,
                                                     const float* __restrict__ upf,
                                                     const float* __restrict__ dnf,
                                                     float* __restrict__ out) {
  extern __shared__ float sm[];
  float* uB  = sm;            // [66][44]
  float* uhB = sm + 2904;     // [66][76]
  float* zB  = sm + 7920;     // [138][76]
  float* dhT = sm;            // [138][36] overlay

  const int blk = blockIdx.x;
  const int half = blk & 1, ch = blk >> 1;
  const int o = ch & 511, b = ch >> 9;
  const float* ybase = ybuf + (size_t)o * NSPAT + b * PLANE;
  const int t = threadIdx.x;
  const int uc0 = half * 32 - 4;   // u window global col start (width 44)

  float f2[12], g[12];
#pragma unroll
  for (int m = 0; m < 12; ++m) { f2[m] = upf[11 - m] * 2.0f; g[m] = dnf[11 - m]; }

  // P1: load u window [66][44], zero-padded outside [0,66)
  for (int e = t; e < 2904; e += 512) {
    int p = e / 44, ul = e - p * 44;
    int uc = uc0 + ul;
    uB[p * 44 + ul] = (uc >= 0 && uc < 66) ? ybase[p * 68 + uc] : 0.f;
  }
  __syncthreads();

  // P2: horizontal upsample. units (p<66, cq<19): uh local cols 4cq..4cq+3
  for (int u = t; u < 1254; u += 512) {
    int p = u / 19, cq = u - p * 19;
    const float* ur = uB + p * 44 + 2 * cq;
    float R0 = ur[0], R1 = ur[1], R2 = ur[2], R3 = ur[3], R4 = ur[4], R5 = ur[5], R6 = ur[6];
    f32x4 o4;
    o4[0] = f2[1]*R0 + f2[3]*R1 + f2[5]*R2 + f2[7]*R3 + f2[9]*R4 + f2[11]*R5;
    o4[1] = f2[0]*R0 + f2[2]*R1 + f2[4]*R2 + f2[6]*R3 + f2[8]*R4 + f2[10]*R5;
    o4[2] = f2[1]*R1 + f2[3]*R2 + f2[5]*R3 + f2[7]*R4 + f2[9]*R5 + f2[11]*R6;
    o4[3] = f2[0]*R1 + f2[2]*R2 + f2[4]*R3 + f2[6]*R4 + f2[8]*R5 + f2[10]*R6;
    *(f32x4*)(uhB + p * 76 + 4 * cq) = o4;
  }
  __syncthreads();

  // P3: vertical upsample + lrelu + clamp. units (e<69, cq<19)
  for (int u = t; u < 1311; u += 512) {
    int e = u / 19, cq = u - e * 19;
    const int coff = 4 * cq;
    f32x4 w[6];
#pragma unroll
    for (int r = 0; r < 6; ++r) {
      int j = e - 4 + r;
      if (j >= 0 && j < 66) w[r] = *(const f32x4*)(uhB + j * 76 + coff);
      else                  w[r] = (f32x4){0.f, 0.f, 0.f, 0.f};
    }
    f32x4 ev = f2[1]*w[0] + f2[3]*w[1] + f2[5]*w[2] + f2[7]*w[3] + f2[9]*w[4] + f2[11]*w[5];
    f32x4 od = f2[0]*w[0] + f2[2]*w[1] + f2[4]*w[2] + f2[6]*w[3] + f2[8]*w[4] + f2[10]*w[5];
    *(f32x4*)(zB + (2 * e) * 76 + coff)     = lrelu_clamp4(ev);
    *(f32x4*)(zB + (2 * e + 1) * 76 + coff) = lrelu_clamp4(od);
  }
  __syncthreads();

  // P4: horizontal downsample -> dhT[tt][local r]. units (tt<138, pi<16): out r0=32h+2pi, r0+1
  for (int u = t; u < 2208; u += 512) {
    int tt = u >> 4, pi = u & 15;
    const float* zr = zB + tt * 76 + 4 * pi;
    f32x4 z0 = *(const f32x4*)zr, z1 = *(const f32x4*)(zr + 4),
          z2 = *(const f32x4*)(zr + 8), z3 = *(const f32x4*)(zr + 12);
    float R[16] = {z0[0],z0[1],z0[2],z0[3], z1[0],z1[1],z1[2],z1[3],
                   z2[0],z2[1],z2[2],z2[3], z3[0],z3[1],z3[2],z3[3]};
    float v0 = 0.f, v1 = 0.f;
#pragma unroll
    for (int i = 0; i < 12; ++i) { v0 += g[i] * R[i]; v1 += g[i] * R[i + 2]; }
    dhT[tt * 36 + 2 * pi]     = v0;
    dhT[tt * 36 + 2 * pi + 1] = v1;
  }
  __syncthreads();

  // P5: vertical downsample -> out. units (s<64, q<8), exactly 512
  {
    int s = t >> 3, q = t & 7;
    const int coff = 4 * q;
    f32x4 acc = {0.f, 0.f, 0.f, 0.f};
#pragma unroll
    for (int i = 0; i < 12; ++i)
      acc += g[i] * *(const f32x4*)(dhT + (2 * s + i) * 36 + coff);
    *(f32x4*)(out + (((size_t)(b * 512 + o)) << 12) + s * 64 + half * 32 + coff) = acc;
  }
}

// ---------------- launcher ----------------
extern "C" void kernel_launch(void* const* d_in, const int* in_sizes, int n_in,
                              void* d_out, int out_size, void* d_ws, size_t ws_size,
                              hipStream_t stream) {
  const float* x     = (const float*)d_in[0];
  const float* w_lat = (const float*)d_in[1];
  const float* convw = (const float*)d_in[2];
  const float* convb = (const float*)d_in[3];
  const float* affw  = (const float*)d_in[4];
  const float* affb  = (const float*)d_in[5];
  const float* upf   = (const float*)d_in[6];
  const float* dnf   = (const float*)d_in[7];
  float* out = (float*)d_out;

  char* ws = (char*)d_ws;
  float* s         = (float*)(ws + 0);
  float* s2        = (float*)(ws + 16384);
  float* rowscale  = (float*)(ws + 32768);
  float* W2        = (float*)(ws + 34816);
  float* dbuf      = (float*)(ws + 1083392);
  unsigned short* wbf = (unsigned short*)(ws + 1099776);
  unsigned short* xhp = (unsigned short*)(ws + 5818368);
  float* ybuf      = (float*)(ws + 43862016);

  styles_kernel<<<16, 256, 0, stream>>>(w_lat, affw, affb, s);
  norm_kernel<<<1, 256, 0, stream>>>(s, s2);
  rowscale_kernel<<<512, 256, 0, stream>>>(convw, rowscale);
  wprep_kernel<<<512, 256, 0, stream>>>(convw, rowscale, wbf, W2);
  demod_kernel<<<16, 256, 0, stream>>>(s2, W2, dbuf);

  hipMemsetAsync(xhp, 0, (size_t)XHP_ROWS * 512 * 2, stream);
  xprep_kernel<<<512, 256, 0, stream>>>(x, s, xhp);

  dim3 cgrid(2, 289);
  conv_kernel<<<cgrid, 256, 73728, stream>>>(wbf, xhp, dbuf, convb, ybuf);

  updown_kernel<<<8192, 512, 73632, stream>>>(ybuf, upf, dnf, out);
}

// Round 5
// 379.800 us; speedup vs baseline: 1.6400x; 1.1234x over previous
//
#include <hip/hip_runtime.h>
#include <stdint.h>

// ---------------- types / helpers ----------------
typedef short short8 __attribute__((ext_vector_type(8)));
typedef float f32x4 __attribute__((ext_vector_type(4)));

__device__ __forceinline__ unsigned short f2bf(float f) {
  union { float f; unsigned u; } v; v.f = f;
  unsigned u = v.u;
  u += 0x7fffu + ((u >> 16) & 1u);   // RNE
  return (unsigned short)(u >> 16);
}

__device__ __forceinline__ void gl16(const void* g, void* l) {
  __builtin_amdgcn_global_load_lds(
      (__attribute__((address_space(1))) void*)(uintptr_t)g,
      (__attribute__((address_space(3))) void*)l, 16, 0, 0);
}

// Problem constants
#define NSPAT 36992
#define PLANE 4624        // 68*68
#define XHP_ROWS 37152    // NSPAT + margin rows

// ---------------- kernel 1: styles ----------------
__global__ void styles_kernel(const float* __restrict__ w_lat, const float* __restrict__ affw,
                              const float* __restrict__ affb, float* __restrict__ s) {
  int g = blockIdx.x * 256 + threadIdx.x;   // 0..4095
  int b = g >> 9, i = g & 511;
  const float4* wl = (const float4*)(w_lat + b * 512);
  const float4* aw = (const float4*)(affw + (size_t)i * 512);
  float acc = 0.f;
#pragma unroll 4
  for (int j = 0; j < 128; ++j) {
    float4 a = wl[j], c = aw[j];
    acc += a.x * c.x + a.y * c.y + a.z * c.z + a.w * c.w;
  }
  s[g] = acc * 0.044194173824159216f + affb[i];
}

// ---------------- kernel 2: global normalize s ----------------
__global__ void norm_kernel(float* __restrict__ s, float* __restrict__ s2) {
  __shared__ float red[256];
  int t = threadIdx.x;
  float acc = 0.f;
  for (int e = t; e < 4096; e += 256) { float v = s[e]; acc += v * v; }
  red[t] = acc; __syncthreads();
  for (int st = 128; st > 0; st >>= 1) {
    if (t < st) red[t] += red[t + st];
    __syncthreads();
  }
  float alpha = rsqrtf(red[0] * (1.0f / 4096.0f));
  for (int e = t; e < 4096; e += 256) {
    float v = s[e] * alpha;
    s[e] = v; s2[e] = v * v;
  }
}

// ---------------- kernel 3: per-output-channel weight scale ----------------
__global__ void rowscale_kernel(const float* __restrict__ convw, float* __restrict__ rowscale) {
  int o = blockIdx.x, t = threadIdx.x;
  const float* wr = convw + (size_t)o * 4608;
  float acc = 0.f;
  for (int e = t; e < 4608; e += 256) { float v = wr[e]; acc += v * v; }
  __shared__ float red[256];
  red[t] = acc; __syncthreads();
  for (int st = 128; st > 0; st >>= 1) {
    if (t < st) red[t] += red[t + st];
    __syncthreads();
  }
  if (t == 0) rowscale[o] = rsqrtf(red[0] * (1.0f / 4608.0f));
}

// ---------------- kernel 4: bf16 weights (tap, o, i) + W2 ----------------
__global__ void wprep_kernel(const float* __restrict__ convw, const float* __restrict__ rowscale,
                             unsigned short* __restrict__ wbf, float* __restrict__ W2) {
  int o = blockIdx.x, t = threadIdx.x;
  float sc = rowscale[o];
  for (int i = t; i < 512; i += 256) {
    const float* wp = convw + ((size_t)o * 512 + i) * 9;
    float w9[9]; float ss = 0.f;
#pragma unroll
    for (int m = 0; m < 9; ++m) { float v = wp[m] * sc; w9[m] = v; ss += v * v; }
    W2[((size_t)o << 9) + i] = ss;
#pragma unroll
    for (int m = 0; m < 9; ++m)
      wbf[(((size_t)m * 512 + o) << 9) + i] = f2bf(w9[m]);
  }
}

// ---------------- kernel 5: demod ----------------
__global__ void demod_kernel(const float* __restrict__ s2, const float* __restrict__ W2,
                             float* __restrict__ dbuf) {
  int g = blockIdx.x * 256 + threadIdx.x;
  int b = g >> 9, o = g & 511;
  const float4* sp = (const float4*)(s2 + b * 512);
  const float4* wp = (const float4*)(W2 + (size_t)o * 512);
  float acc = 1e-8f;
#pragma unroll 4
  for (int j = 0; j < 128; ++j) {
    float4 a = sp[j], c = wp[j];
    acc += a.x * c.x + a.y * c.y + a.z * c.z + a.w * c.w;
  }
  dbuf[g] = rsqrtf(acc);
}

// ---------------- kernel 6: x-hat NHWC padded bf16 ----------------
__global__ void xprep_kernel(const float* __restrict__ x, const float* __restrict__ s,
                             unsigned short* __restrict__ xhp) {
  int b = blockIdx.x >> 6, h = blockIdx.x & 63;
  int t = threadIdx.x;
  __shared__ float tile[64 * 65];
  __shared__ float sv[64];
  for (int it = 0; it < 8; ++it) {
    int i0 = it * 64;
    {
      int ii = t >> 2, wseg = (t & 3) * 16;
      const float4* src = (const float4*)(x + (((size_t)(b * 512 + i0 + ii) * 64 + h) << 6) + wseg);
      float4 v0 = src[0], v1 = src[1], v2 = src[2], v3 = src[3];
      float* dst = tile + ii * 65 + wseg;
      dst[0]=v0.x; dst[1]=v0.y; dst[2]=v0.z; dst[3]=v0.w;
      dst[4]=v1.x; dst[5]=v1.y; dst[6]=v1.z; dst[7]=v1.w;
      dst[8]=v2.x; dst[9]=v2.y; dst[10]=v2.z; dst[11]=v2.w;
      dst[12]=v3.x; dst[13]=v3.y; dst[14]=v3.z; dst[15]=v3.w;
    }
    if (t < 64) sv[t] = s[b * 512 + i0 + t];
    __syncthreads();
    {
      int w = t >> 2, ic = (t & 3) * 16;
      alignas(16) unsigned short tmp[16];
#pragma unroll
      for (int k = 0; k < 16; ++k)
        tmp[k] = f2bf(tile[(ic + k) * 65 + w] * sv[ic + k]);
      unsigned short* dst = xhp + ((size_t)b * PLANE + (h + 2) * 68 + (w + 2)) * 512 + i0 + ic;
      *(short8*)dst = *(const short8*)tmp;
      *(short8*)(dst + 8) = *(const short8*)(tmp + 8);
    }
    __syncthreads();
  }
}

// ---------------- kernel 7: implicit-GEMM conv, 128x128 tile (R3 structure) ----------------
// 3-deep counted-vmcnt pipeline (T4) + XOR LDS swizzle (T2) + setprio around MFMA (T5 A/B)
__global__ __launch_bounds__(256, 3) void conv_kernel(const unsigned short* __restrict__ wbf,
                                                      const unsigned short* __restrict__ xhp,
                                                      const float* __restrict__ dbuf,
                                                      const float* __restrict__ convb,
                                                      float* __restrict__ ybuf) {
  __shared__ unsigned short lds[24576];  // 3 bufs x (A 4096 + B 4096) shorts = 48 KB
  const int t = threadIdx.x;
  const int lane = t & 63, wid = t >> 6;

  // n-major order + bijective XCD chunking: orig = ntile*4 + otile
  int orig = blockIdx.y * 4 + blockIdx.x;
  int xcd = orig & 7, idx = orig >> 3;
  int wg = (xcd < 4) ? (xcd * 145 + idx) : (580 + (xcd - 4) * 144 + idx);
  const int n0 = (wg >> 2) * 128, o0 = (wg & 3) * 128;
  const int wm = wid >> 1, wn = wid & 1;

  // staging: lane l loads global quarter q = (l&3) ^ ((l>>3)&3) of its row
  const unsigned kc = (((unsigned)(lane & 3)) ^ ((unsigned)(lane >> 3) & 3u)) * 8u;
  const unsigned aOff0 = (unsigned)(o0 + wid * 32 + (lane >> 2)) * 512 + kc;
  const unsigned aOff1 = aOff0 + 16 * 512;
  const unsigned bOff0 = (unsigned)(n0 + wid * 32 + (lane >> 2)) * 512 + kc;
  const unsigned bOff1 = bOff0 + 16 * 512;

  // frag read: row r=lane&15, phys quarter = (lane>>4) ^ ((r>>1)&3)
  const unsigned xq = ((unsigned)(lane >> 4)) ^ (((unsigned)(lane & 15) >> 1) & 3u);
  const unsigned aFo = wm * 2048 + (lane & 15) * 32 + xq * 8;
  const unsigned bFo = 4096 + wn * 2048 + (lane & 15) * 32 + xq * 8;

  f32x4 acc[4][4] = {};

#define STAGE(stp, off) do {                                           \
    const unsigned tp = (unsigned)(stp) >> 4;                          \
    const unsigned k0 = ((unsigned)(stp) & 15u) * 32u;                 \
    const unsigned aT = tp * 262144u + k0;                             \
    const unsigned bS = ((tp / 3u) * 68u + (tp % 3u)) * 512u + k0;     \
    unsigned short* la = lds + (off) + wid * 1024;                     \
    unsigned short* lb = lds + (off) + 4096 + wid * 1024;              \
    gl16(wbf + aT + aOff0, la);                                        \
    gl16(wbf + aT + aOff1, la + 512);                                  \
    gl16(xhp + bS + bOff0, lb);                                        \
    gl16(xhp + bS + bOff1, lb + 512);                                  \
  } while (0)

#define COMPUTE(rdoff) do {                                            \
    const unsigned short* aF = lds + (rdoff) + aFo;                    \
    const unsigned short* bF = lds + (rdoff) + bFo;                    \
    short8 a0 = *(const short8*)(aF + 0);                              \
    short8 a1 = *(const short8*)(aF + 512);                            \
    short8 a2 = *(const short8*)(aF + 1024);                           \
    short8 a3 = *(const short8*)(aF + 1536);                           \
    short8 b0 = *(const short8*)(bF + 0);                              \
    short8 b1 = *(const short8*)(bF + 512);                            \
    short8 b2 = *(const short8*)(bF + 1024);                           \
    short8 b3 = *(const short8*)(bF + 1536);                           \
    __builtin_amdgcn_s_setprio(1);                                     \
    acc[0][0] = __builtin_amdgcn_mfma_f32_16x16x32_bf16(a0, b0, acc[0][0], 0, 0, 0); \
    acc[0][1] = __builtin_amdgcn_mfma_f32_16x16x32_bf16(a0, b1, acc[0][1], 0, 0, 0); \
    acc[0][2] = __builtin_amdgcn_mfma_f32_16x16x32_bf16(a0, b2, acc[0][2], 0, 0, 0); \
    acc[0][3] = __builtin_amdgcn_mfma_f32_16x16x32_bf16(a0, b3, acc[0][3], 0, 0, 0); \
    acc[1][0] = __builtin_amdgcn_mfma_f32_16x16x32_bf16(a1, b0, acc[1][0], 0, 0, 0); \
    acc[1][1] = __builtin_amdgcn_mfma_f32_16x16x32_bf16(a1, b1, acc[1][1], 0, 0, 0); \
    acc[1][2] = __builtin_amdgcn_mfma_f32_16x16x32_bf16(a1, b2, acc[1][2], 0, 0, 0); \
    acc[1][3] = __builtin_amdgcn_mfma_f32_16x16x32_bf16(a1, b3, acc[1][3], 0, 0, 0); \
    acc[2][0] = __builtin_amdgcn_mfma_f32_16x16x32_bf16(a2, b0, acc[2][0], 0, 0, 0); \
    acc[2][1] = __builtin_amdgcn_mfma_f32_16x16x32_bf16(a2, b1, acc[2][1], 0, 0, 0); \
    acc[2][2] = __builtin_amdgcn_mfma_f32_16x16x32_bf16(a2, b2, acc[2][2], 0, 0, 0); \
    acc[2][3] = __builtin_amdgcn_mfma_f32_16x16x32_bf16(a2, b3, acc[2][3], 0, 0, 0); \
    acc[3][0] = __builtin_amdgcn_mfma_f32_16x16x32_bf16(a3, b0, acc[3][0], 0, 0, 0); \
    acc[3][1] = __builtin_amdgcn_mfma_f32_16x16x32_bf16(a3, b1, acc[3][1], 0, 0, 0); \
    acc[3][2] = __builtin_amdgcn_mfma_f32_16x16x32_bf16(a3, b2, acc[3][2], 0, 0, 0); \
    acc[3][3] = __builtin_amdgcn_mfma_f32_16x16x32_bf16(a3, b3, acc[3][3], 0, 0, 0); \
    __builtin_amdgcn_s_setprio(0);                                     \
  } while (0)

  STAGE(0, 0u);
  STAGE(1, 8192u);

  unsigned rd = 0, wr2 = 16384;
  for (int step = 0; step < 143; ++step) {
    asm volatile("s_waitcnt vmcnt(4)" ::: "memory");   // oldest stage's 4 loads done
    __builtin_amdgcn_s_barrier();
    asm volatile("" ::: "memory");
    if (step < 142) STAGE(step + 2, wr2);
    COMPUTE(rd);
    asm volatile("" ::: "memory");
    rd += 8192;  if (rd == 24576) rd = 0;
    wr2 += 8192; if (wr2 == 24576) wr2 = 0;
  }
  asm volatile("s_waitcnt vmcnt(0)" ::: "memory");
  __builtin_amdgcn_s_barrier();
  asm volatile("" ::: "memory");
  COMPUTE(rd);
#undef STAGE
#undef COMPUTE

  // epilogue
  const int col = lane & 15;
  const int rbase = (lane >> 4) * 4;
#pragma unroll
  for (int ni = 0; ni < 4; ++ni) {
    const unsigned n = (unsigned)(n0 + wn * 64 + ni * 16 + col);
    const unsigned b = n / 4624u;
    const float* dr = dbuf + b * 512;
#pragma unroll
    for (int mi = 0; mi < 4; ++mi) {
      const int ob = o0 + wm * 64 + mi * 16 + rbase;
#pragma unroll
      for (int j = 0; j < 4; ++j) {
        const int o = ob + j;
        float v = acc[mi][ni][j] * dr[o] + convb[o];
        v = fminf(fmaxf(v, -256.f), 256.f);
        ybuf[(size_t)o * NSPAT + n] = v;
      }
    }
  }
}

// ---------------- kernel 8: fused up2 + lrelu + down2, z kept in registers ----------------
// Down filters commute (separable): do v-up + lrelu + v-down fused per column, then h-down.
// 2 blocks per channel (output col halves). LDS: uhB[66][76] | uB[66][44] / dvT[64][76] overlay.
// Peak 9880 floats = 39.5 KB -> 4 blocks/CU.
__global__ __launch_bounds__(256, 4) void updown_kernel(const float* __restrict__ ybuf,
                                                        const float* __restrict__ upf,
                                                        const float* __restrict__ dnf,
                                                        float* __restrict__ out) {
  __shared__ float sm[9880];
  float* uhB = sm;            // [66][76]
  float* uB  = sm + 5016;     // [66][44]
  float* dvT = sm + 5016;     // [64][76] overlay (uB dead after P2)

  const int blk = blockIdx.x;
  const int half = blk & 1, ch = blk >> 1;
  const int o = ch & 511, b = ch >> 9;
  const float* ybase = ybuf + (size_t)o * NSPAT + b * PLANE;
  const int t = threadIdx.x;
  const int uc0 = half * 32 - 4;   // u window global col start (width 44)

  float f2[12], g[12];
#pragma unroll
  for (int m = 0; m < 12; ++m) { f2[m] = upf[11 - m] * 2.0f; g[m] = dnf[11 - m]; }

  // P1: load u window [66][44] via f32x4, zero-masked outside valid cols [0,66)
  for (int u = t; u < 726; u += 256) {
    int p = u / 11, q = u - p * 11;
    int gc = uc0 + 4 * q;
    f32x4 v = {0.f, 0.f, 0.f, 0.f};
    if (gc >= 0 && gc < 66) {
      v = *(const f32x4*)(ybase + p * 68 + gc);
#pragma unroll
      for (int j = 0; j < 4; ++j)
        if (gc + j >= 66) v[j] = 0.f;
    }
    *(f32x4*)(uB + p * 44 + 4 * q) = v;
  }
  __syncthreads();

  // P2: horizontal upsample. units (p<66, cq<19): uh local cols 4cq..4cq+3
  for (int u = t; u < 1254; u += 256) {
    int p = u / 19, cq = u - p * 19;
    const float* ur = uB + p * 44 + 2 * cq;
    float R0 = ur[0], R1 = ur[1], R2 = ur[2], R3 = ur[3], R4 = ur[4], R5 = ur[5], R6 = ur[6];
    f32x4 o4;
    o4[0] = f2[1]*R0 + f2[3]*R1 + f2[5]*R2 + f2[7]*R3 + f2[9]*R4 + f2[11]*R5;
    o4[1] = f2[0]*R0 + f2[2]*R1 + f2[4]*R2 + f2[6]*R3 + f2[8]*R4 + f2[10]*R5;
    o4[2] = f2[1]*R1 + f2[3]*R2 + f2[5]*R3 + f2[7]*R4 + f2[9]*R5 + f2[11]*R6;
    o4[3] = f2[0]*R1 + f2[2]*R2 + f2[4]*R3 + f2[6]*R4 + f2[8]*R5 + f2[10]*R6;
    *(f32x4*)(uhB + p * 76 + 4 * cq) = o4;
  }
  __syncthreads();

  // P3': fused vertical up + lrelu + vertical down, per column, z in registers.
  // units (cl<75, sg<3): s range [22sg, 22sg+21] clipped to <64
  if (t < 225) {
    const int cl = t % 75, sg = t / 75;
    const int s0 = sg * 22;
    const int ttg0 = 2 * s0;
    float R[32];
#pragma unroll
    for (int k = 0; k < 32; ++k) {
      int j = s0 - 4 + k;
      R[k] = (j >= 0 && j < 66) ? uhB[j * 76 + cl] : 0.f;
    }
    float dv[22];
#pragma unroll
    for (int m = 0; m < 22; ++m) dv[m] = 0.f;
#pragma unroll
    for (int k = 0; k < 54; ++k) {
      const int kb = k >> 1;
      float z;
      if (k & 1)
        z = f2[0]*R[kb] + f2[2]*R[kb+1] + f2[4]*R[kb+2] + f2[6]*R[kb+3] + f2[8]*R[kb+4] + f2[10]*R[kb+5];
      else
        z = f2[1]*R[kb] + f2[3]*R[kb+1] + f2[5]*R[kb+2] + f2[7]*R[kb+3] + f2[9]*R[kb+4] + f2[11]*R[kb+5];
      z = (z > 0.f ? z : 0.2f * z) * 1.4142135623730951f;
      z = fminf(fmaxf(z, -256.f), 256.f);
      if (ttg0 + k >= 138) z = 0.f;   // rows beyond z extent (only feeds unwritten dv)
      const int mlo = (k < 11) ? 0 : ((k - 10) >> 1);
      const int mhi = ((k >> 1) < 21) ? (k >> 1) : 21;
#pragma unroll
      for (int m = mlo; m <= mhi; ++m)
        dv[m] += g[k - 2 * m] * z;
    }
#pragma unroll
    for (int m = 0; m < 22; ++m) {
      const int s = s0 + m;
      if (s < 64) dvT[s * 76 + cl] = dv[m];
    }
  }
  __syncthreads();

  // P4': horizontal downsample + store. units (s<64, rq<4): out cols 32h+8rq..+7, exactly 256
  {
    const int s = t >> 2, rq = t & 3;
    const float* dr = dvT + s * 76 + 16 * rq;
    f32x4 dd[7];
#pragma unroll
    for (int i = 0; i < 7; ++i) dd[i] = *(const f32x4*)(dr + 4 * i);
    float D[28];
#pragma unroll
    for (int i = 0; i < 7; ++i) {
      D[4*i+0] = dd[i][0]; D[4*i+1] = dd[i][1]; D[4*i+2] = dd[i][2]; D[4*i+3] = dd[i][3];
    }
    f32x4 o0, o1;
#pragma unroll
    for (int m = 0; m < 8; ++m) {
      float v = g[0]*D[2*m] + g[1]*D[2*m+1] + g[2]*D[2*m+2] + g[3]*D[2*m+3]
              + g[4]*D[2*m+4] + g[5]*D[2*m+5] + g[6]*D[2*m+6] + g[7]*D[2*m+7]
              + g[8]*D[2*m+8] + g[9]*D[2*m+9] + g[10]*D[2*m+10] + g[11]*D[2*m+11];
      if (m < 4) o0[m] = v; else o1[m - 4] = v;
    }
    float* ob = out + (((size_t)(b * 512 + o)) << 12) + s * 64 + half * 32 + 8 * rq;
    *(f32x4*)ob = o0;
    *(f32x4*)(ob + 4) = o1;
  }
}

// ---------------- launcher ----------------
extern "C" void kernel_launch(void* const* d_in, const int* in_sizes, int n_in,
                              void* d_out, int out_size, void* d_ws, size_t ws_size,
                              hipStream_t stream) {
  const float* x     = (const float*)d_in[0];
  const float* w_lat = (const float*)d_in[1];
  const float* convw = (const float*)d_in[2];
  const float* convb = (const float*)d_in[3];
  const float* affw  = (const float*)d_in[4];
  const float* affb  = (const float*)d_in[5];
  const float* upf   = (const float*)d_in[6];
  const float* dnf   = (const float*)d_in[7];
  float* out = (float*)d_out;

  char* ws = (char*)d_ws;
  float* s         = (float*)(ws + 0);
  float* s2        = (float*)(ws + 16384);
  float* rowscale  = (float*)(ws + 32768);
  float* W2        = (float*)(ws + 34816);
  float* dbuf      = (float*)(ws + 1083392);
  unsigned short* wbf = (unsigned short*)(ws + 1099776);
  unsigned short* xhp = (unsigned short*)(ws + 5818368);
  float* ybuf      = (float*)(ws + 43862016);

  styles_kernel<<<16, 256, 0, stream>>>(w_lat, affw, affb, s);
  norm_kernel<<<1, 256, 0, stream>>>(s, s2);
  rowscale_kernel<<<512, 256, 0, stream>>>(convw, rowscale);
  wprep_kernel<<<512, 256, 0, stream>>>(convw, rowscale, wbf, W2);
  demod_kernel<<<16, 256, 0, stream>>>(s2, W2, dbuf);

  hipMemsetAsync(xhp, 0, (size_t)XHP_ROWS * 512 * 2, stream);
  xprep_kernel<<<512, 256, 0, stream>>>(x, s, xhp);

  dim3 cgrid(4, 289);
  conv_kernel<<<cgrid, 256, 0, stream>>>(wbf, xhp, dbuf, convb, ybuf);

  updown_kernel<<<8192, 256, 0, stream>>>(ybuf, upf, dnf, out);
}